// Round 14
// baseline (561.307 us; speedup 1.0000x reference)
//
#include <hip/hip_runtime.h>

#define AA 256
#define EE 256
#define CC (AA + EE + AA*EE)   // 66048
#define TT 1024
#define VV 1024
#define NSTRIP 16
#define NCHUNKS 36             // 36 chunks x 16 supersteps = 576 supersteps
#define NEGBIG (-3.0e38f)      // finite stand-in for -inf in outputs
#define INVLN2 1.44269504088896340736f
#define LN2F   0.69314718055994530942f
#define SENT   0x7FC00001u     // NaN-payload sentinel for bnd
#define NINF   (-__builtin_inff())

#define E2(x) __builtin_amdgcn_exp2f(x)  // native v_exp_f32: 2^x
#define L2(x) __builtin_amdgcn_logf(x)   // native v_log_f32: log2(x)

__device__ __forceinline__ float safe_out(float v) {
    if (!(v > NEGBIG)) return NEGBIG;   // catches -inf, NaN
    return v;
}

// ---------------- init: bnd sentinel + W2 = W/ln2 ----------------
__global__ void k_init(const float* __restrict__ W, float* __restrict__ W2,
                       unsigned* __restrict__ bndu) {
    int i = blockIdx.x * 256 + threadIdx.x;
    if (i < CC) W2[i] = W[i] * INVLN2;
    if (i < 32 * 1024) bndu[i] = SENT;
}

// ---------------- CSR build: rows by ar-symbol, cols by en-symbol ----------------
__global__ __launch_bounds__(1024)
void k_csr(const int* __restrict__ ar, const int* __restrict__ en,
           int* __restrict__ offA, int* __restrict__ rowsA,
           int* __restrict__ offE, int* __restrict__ colsE) {
    __shared__ int cA[256], cE[256], oA[257], oE[257];
    int tid = threadIdx.x;
    if (tid < 256) { cA[tid] = 0; cE[tid] = 0; }
    __syncthreads();
    int a_ = (tid >= 1) ? ar[tid] : 0;
    int e_ = (tid >= 1) ? en[tid] : 0;
    if (tid >= 1) { atomicAdd(&cA[a_], 1); atomicAdd(&cE[e_], 1); }
    __syncthreads();
    if (tid == 0) { int s = 0; for (int i = 0; i < 256; ++i) { oA[i] = s; s += cA[i]; } oA[256] = s; }
    if (tid == 1) { int s = 0; for (int i = 0; i < 256; ++i) { oE[i] = s; s += cE[i]; } oE[256] = s; }
    __syncthreads();
    if (tid < 256) { cA[tid] = 0; cE[tid] = 0; }
    __syncthreads();
    if (tid >= 1) {
        rowsA[oA[a_] + atomicAdd(&cA[a_], 1)] = tid;
        colsE[oE[e_] + atomicAdd(&cE[e_], 1)] = tid;
    }
    if (tid < 257) { offA[tid] = oA[tid]; offE[tid] = oE[tid]; }
}

// ---------------- pipelined strip DP: 32 blocks x 1 wave, 2 cells/lane/superstep ----------------
// LSE5 trick: VB = LSE(delb, subb, wi_b+VA) == LSE5(delb, subb, wi_b+dela, wi_b+suba,
// wi_b+insa) -- VA and VB compute in parallel, per-superstep chain = ONE LSE.
// XCD-aware mapping; row-major direct float2 stores (round-12 proven).
__global__ __launch_bounds__(64)
void k_dp_strip(const float* __restrict__ W2, const int* __restrict__ ar,
                const int* __restrict__ en,
                float* __restrict__ alpha, float* __restrict__ beta,
                float* __restrict__ bnd) {
    __shared__ float ws_lds[256 * 64];          // [e][row], 64KB
    __shared__ float wi_s[1312];                // col = idx-128, valid 1..1023
    __shared__ int   en_s[1312];
    __shared__ float seed_s[1024];
    __shared__ float pub[2][32];                // bottom-row collect by column
    const int tid = threadIdx.x;
    const int B = blockIdx.x;                   // 0..31
    const int xcd = B & 7, slot = B >> 3;
    const int dir = xcd >> 2;
    const int b = ((xcd & 3) << 2) + slot;      // strip 0..15
    const int dirb = (dir << 4) + b;
    const bool fwd = (dir == 0);
    const bool seedstrip = (b == 0);
    const int rr = (b << 6) + tid;

    for (int x = tid; x < 1312; x += 64) {
        int col = x - 128;
        bool valid = (col >= 1 && col <= 1023);
        int e = valid ? en[fwd ? col : 1024 - col] : 0;
        en_s[x] = e;
        wi_s[x] = valid ? W2[AA + e] : 0.0f;
    }

    const int r_src = (rr >= 1) ? (fwd ? rr : (1024 - rr)) : 0;
    const float mywd2 = (rr >= 1) ? W2[ar[r_src]] : 0.0f;
    {   // stage this lane's substitution row into LDS [e][tid]
        const float* wrow = W2 + AA + EE + ((rr >= 1) ? (ar[r_src] << 8) : 0);
        #pragma unroll 8
        for (int i = 0; i < 64; ++i) {
            float4 w = *(const float4*)(wrow + (i << 2));
            ws_lds[((i << 2) + 0) * 64 + tid] = w.x;
            ws_lds[((i << 2) + 1) * 64 + tid] = w.y;
            ws_lds[((i << 2) + 2) * 64 + tid] = w.z;
            ws_lds[((i << 2) + 3) * 64 + tid] = w.w;
        }
    }

    if (seedstrip) {   // seed_s[x] = sum_{c=1..x} wi_s[128+c]
        float loc[16]; float s = 0.0f;
        #pragma unroll
        for (int i = 0; i < 16; ++i) {
            int x = (tid << 4) + i;
            float w = (x >= 1) ? wi_s[128 + x] : 0.0f;
            s += w; loc[i] = s;
        }
        float cum = s;
        for (int off = 1; off < 64; off <<= 1) {
            float tt = __shfl_up(cum, off);
            if (tid >= off) cum += tt;
        }
        float excl = cum - s;
        #pragma unroll
        for (int i = 0; i < 16; ++i) seed_s[(tid << 4) + i] = excl + loc[i];
    }
    __syncthreads();

    const int outrow = fwd ? (rr << 10) : ((1023 - rr) << 10);
    float* __restrict__ obase = fwd ? alpha : beta;
    float* __restrict__ bnd_me = bnd + (size_t)dirb * 1024;
    const float* __restrict__ bnd_prev = bnd + (size_t)(dirb - 1) * 1024;
    const bool seedlane = seedstrip && (tid == 0);

    float vA = NINF, vB = NINF, upBp = NINF;
    int2   env[8];   // en pairs, prefetched 8 supersteps ahead
    float2 wiv[4];   // wi pairs, 4 ahead
    float2 wsv[4];   // ws pairs, 4 ahead
    #pragma unroll
    for (int s = 0; s < 8; ++s) env[s] = *(const int2*)&en_s[128 + 2 * s - 2 * tid];
    #pragma unroll
    for (int s = 0; s < 4; ++s) wiv[s] = *(const float2*)&wi_s[128 + 2 * s - 2 * tid];
    #pragma unroll
    for (int s = 0; s < 4; ++s)
        wsv[s] = make_float2(ws_lds[(env[s].x << 6) + tid], ws_lds[(env[s].y << 6) + tid]);

    float bvals = NINF;

    for (int c = 0; c < NCHUNKS; ++c) {
        // ---- fetch boundary cols 32c..32c+31 (consumer) ----
        if (c <= 31) {
            if (seedstrip) {
                bvals = seed_s[(c << 5) + (tid & 31)];
            } else {
                const float* src = bnd_prev + (c << 5) + (tid & 31);
                unsigned x;
                for (;;) {
                    asm volatile("global_load_dword %0, %1, off sc0 sc1\n\t"
                                 "s_waitcnt vmcnt(0)"
                                 : "=v"(x) : "v"(src) : "memory");
                    if (__ballot(x != SENT) == ~0ull) break;
                    __builtin_amdgcn_s_sleep(1);
                }
                bvals = __uint_as_float(x);
            }
        }
        #pragma unroll
        for (int k = 0; k < 16; ++k) {
            const int S = (c << 4) + k;
            const int sd = S - tid;                  // a = 2*sd
            const bool act = ((unsigned)sd < 512u);
            float bca = __int_as_float(__builtin_amdgcn_readlane(__float_as_int(bvals), 2 * k));
            float bcb = __int_as_float(__builtin_amdgcn_readlane(__float_as_int(bvals), 2 * k + 1));
            float upA = __int_as_float(__builtin_amdgcn_update_dpp(
                __float_as_int(bca), __float_as_int(vA), 0x138, 0xF, 0xF, false));
            float upB = __int_as_float(__builtin_amdgcn_update_dpp(
                __float_as_int(bcb), __float_as_int(vB), 0x138, 0xF, 0xF, false));
            float2 wsp = wsv[k & 3];
            float2 wip = wiv[k & 3];
            // software pipelines (issue early; LDS only)
            int2   ep  = *(const int2*)&en_s[128 + 2 * S + 16 - 2 * tid];    // for S+8
            float2 win = *(const float2*)&wi_s[128 + 2 * S + 8 - 2 * tid];   // for S+4
            int2   ec  = env[(k + 4) & 7];                                   // en for S+4
            float  wsx = ws_lds[(ec.x << 6) + tid];
            float  wsy = ws_lds[(ec.y << 6) + tid];

            // terms for cell a (all from prev-superstep registers)
            float dela = mywd2 + upA;                // wd + V(r-1, a)
            float suba = wsp.x + upBp;               // ws[a] + V(r-1, a-1)
            float insa = wip.x + vB;                 // wi[a] + V(r, a-1)
            // VA = LSE3 (parallel)
            float mA = fmaxf(fmaxf(dela, suba), insa);
            float sA = E2(dela - mA) + E2(suba - mA) + E2(insa - mA);
            float VA = mA + L2(sA);
            // VB = LSE5 (parallel, no VA dependency)
            float delb = mywd2 + upB;                // wd + V(r-1, b)
            float subb = wsp.y + upA;                // ws[b] + V(r-1, a)
            float t3 = wip.y + dela, t4 = wip.y + suba, t5 = wip.y + insa;
            float mB = fmaxf(fmaxf(fmaxf(delb, subb), t3), fmaxf(t4, t5));
            float sB = E2(delb - mB) + E2(subb - mB) + E2(t3 - mB) + E2(t4 - mB) + E2(t5 - mB);
            float VB = mB + L2(sB);

            VA = seedlane ? bca : VA;  VA = act ? VA : NINF;
            VB = seedlane ? bcb : VB;  VB = act ? VB : NINF;

            env[(k + 8) & 7] = ep;
            wiv[(k + 4) & 3] = win;
            wsv[(k + 4) & 3] = make_float2(wsx, wsy);

            if (act) {
                const int a = 2 * sd;
                if (tid == 63)                        // bottom-row collect by column
                    *(float2*)&pub[(a >> 5) & 1][a & 31] = make_float2(VA, VB);
                if (fwd) *(float2*)(obase + outrow + a) = make_float2(VA, VB);
                else     *(float2*)(obase + outrow + (1022 - a)) = make_float2(VB, VA);
            }
            upBp = upB; vA = VA; vB = VB;
        }
        // ---- publish col-chunk q=c-4 (complete as of superstep 16c+15) ----
        if (b < NSTRIP - 1 && c >= 4) {
            const int q = c - 4;
            float pv = pub[q & 1][tid & 31];
            if (tid < 32) {
                const float* dst = bnd_me + (q << 5) + tid;
                asm volatile("global_store_dword %0, %1, off sc0 sc1"
                             :: "v"(dst), "v"(__float_as_uint(pv)) : "memory");
            }
        }
    }
}

// ---------------- block reduce helpers (256 threads = 4 waves) ----------------
__device__ __forceinline__ float blk_max(float v, float* sm) {
    for (int off = 32; off > 0; off >>= 1) v = fmaxf(v, __shfl_xor(v, off));
    if ((threadIdx.x & 63) == 0) sm[threadIdx.x >> 6] = v;
    __syncthreads();
    float r = fmaxf(fmaxf(sm[0], sm[1]), fmaxf(sm[2], sm[3]));
    __syncthreads();
    return r;
}
__device__ __forceinline__ float blk_sum(float v, float* sm) {
    for (int off = 32; off > 0; off >>= 1) v += __shfl_xor(v, off);
    if ((threadIdx.x & 63) == 0) sm[threadIdx.x >> 6] = v;
    __syncthreads();
    float r = sm[0] + sm[1] + sm[2] + sm[3];
    __syncthreads();
    return r;
}

// ---------------- fused per-a epilogue: sub bins + dbins, no atomics ----------------
// Block a processes rows {t: ar[t]=a}: stages alpha[t-1], beta[t] in LDS;
// thread e accumulates online LSE over its en-CSR columns; rowred+dbins fused.
__global__ __launch_bounds__(256)
void k_sub(const float* __restrict__ alpha, const float* __restrict__ beta,
           const float* __restrict__ W,
           const int* __restrict__ offA, const int* __restrict__ rowsA,
           const int* __restrict__ offE, const int* __restrict__ colsE,
           float* __restrict__ out) {
    __shared__ float als[1024], bts[1024];
    __shared__ float sm[4];
    const int a = blockIdx.x;
    const int tid = threadIdx.x;
    const int ra0 = offA[a], ra1 = offA[a + 1];
    const int je0 = offE[tid], je1 = offE[tid + 1];
    float me = NINF, se = 0.0f;     // sub bin (a, e=tid)
    float dm = NINF, ds_ = 0.0f;    // dbins(a) online over rowred

    for (int idx = ra0; idx < ra1; ++idx) {
        const int t = rowsA[idx];
        for (int x = tid; x < 1024; x += 256) {
            als[x] = alpha[(size_t)(t - 1) * 1024 + x];
            bts[x] = beta[(size_t)t * 1024 + x];
        }
        __syncthreads();
        // rowred[t] = LSE2_j(als[j]+bts[j])
        float v0[4]; float lm = NINF;
        #pragma unroll
        for (int i = 0; i < 4; ++i) {
            int j = tid + (i << 8);
            v0[i] = als[j] + bts[j];
            lm = fmaxf(lm, v0[i]);
        }
        float m = blk_max(lm, sm);
        float ls = 0.0f;
        #pragma unroll
        for (int i = 0; i < 4; ++i) ls += E2(v0[i] - m);
        float s = blk_sum(ls, sm);
        float rv = m + L2(s);
        if (rv <= dm) ds_ += E2(rv - dm);
        else { ds_ = ds_ * E2(dm - rv) + 1.0f; dm = rv; }
        // sub contributions: thread e over its columns
        for (int p = je0; p < je1; ++p) {
            int j = colsE[p];
            float v = als[j - 1] + bts[j];
            if (v <= me) se += E2(v - me);
            else { se = se * E2(me - v) + 1.0f; me = v; }
        }
        __syncthreads();
    }
    int id = AA + EE + (a << 8) + tid;
    out[id] = (me == NINF) ? NEGBIG : safe_out(W[id] + LN2F * (me + L2(se)));
    if (tid == 0)
        out[a] = (dm == NINF) ? NEGBIG : safe_out(W[a] + LN2F * (dm + L2(ds_)));
}

// ---------------- insert col reduction, stage 1: partials over 128-row bands ----------------
__global__ __launch_bounds__(256)
void k_colpart(const float* __restrict__ alpha, const float* __restrict__ beta,
               float* __restrict__ cpm, float* __restrict__ cps) {
    __shared__ float smm[4][64], sms[4][64];
    int c = threadIdx.x & 63;
    int g = threadIdx.x >> 6;
    int j = (blockIdx.x << 6) + c;
    int t0 = blockIdx.y << 7;
    float m = NINF, s = 0.0f;
    if (j >= 1) {
        for (int t = t0 + g; t < t0 + 128; t += 4) {
            float v = alpha[(size_t)t * 1024 + (j - 1)] + beta[(size_t)t * 1024 + j];
            if (v <= m) s += E2(v - m);
            else { s = s * E2(m - v) + 1.0f; m = v; }
        }
    }
    smm[g][c] = m; sms[g][c] = s;
    __syncthreads();
    if (g == 0) {
        float M = m, S = s;
        for (int k = 1; k < 4; ++k) {
            float mk = smm[k][c], sk = sms[k][c];
            if (mk <= M) S += sk * E2(mk - M);
            else { S = S * E2(M - mk) + sk; M = mk; }
        }
        cpm[(size_t)blockIdx.y * 1024 + j] = M;
        cps[(size_t)blockIdx.y * 1024 + j] = S;
    }
}
// stage 2: merge 8 bands
__global__ void k_colfin(const float* __restrict__ cpm, const float* __restrict__ cps,
                         float* __restrict__ colred) {
    int j = blockIdx.x * 256 + threadIdx.x;
    float M = NINF, S = 0.0f;
    for (int k = 0; k < 8; ++k) {
        float mk = cpm[(size_t)k * 1024 + j], sk = cps[(size_t)k * 1024 + j];
        if (mk <= M) S += sk * E2(mk - M);
        else { S = S * E2(M - mk) + sk; M = mk; }
    }
    colred[j] = (j >= 1) ? (M + L2(S)) : NINF;
}

// ---------------- ibins: bin colred by en ----------------
__global__ __launch_bounds__(256)
void k_ibins(const int* __restrict__ en, const float* __restrict__ colred,
             const float* __restrict__ W, float* __restrict__ out) {
    __shared__ float cv[1024]; __shared__ int ev[1024];
    int tid = threadIdx.x;
    for (int x = tid; x < 1024; x += 256) { cv[x] = colred[x]; ev[x] = en[x]; }
    __syncthreads();
    float m = NINF, s = 0.0f;
    for (int j = 1; j < 1024; ++j) {
        if (ev[j] == tid) {
            float v = cv[j];
            if (v <= m) s += E2(v - m);
            else { s = s * E2(m - v) + 1.0f; m = v; }
        }
    }
    out[AA + tid] = (m == NINF) ? NEGBIG : safe_out(W[AA + tid] + LN2F * (m + L2(s)));
}

extern "C" void kernel_launch(void* const* d_in, const int* in_sizes, int n_in,
                              void* d_out, int out_size, void* d_ws, size_t ws_size,
                              hipStream_t stream) {
    const float* W  = (const float*)d_in[0];
    const int*   ar = (const int*)d_in[1];
    const int*   en = (const int*)d_in[2];
    float* out = (float*)d_out;

    char* p = (char*)d_ws;
    float* W2      = (float*)p; p += (size_t)CC * 4;
    float* alpha   = (float*)p; p += (size_t)TT * VV * 4;
    float* beta    = (float*)p; p += (size_t)TT * VV * 4;
    float* bnd     = (float*)p; p += (size_t)32 * 1024 * 4;
    float* colred  = (float*)p; p += VV * 4;
    float* cpm     = (float*)p; p += (size_t)8 * 1024 * 4;
    float* cps     = (float*)p; p += (size_t)8 * 1024 * 4;
    int*   offA    = (int*)p;   p += 257 * 4;
    int*   rowsA   = (int*)p;   p += 1024 * 4;
    int*   offE    = (int*)p;   p += 257 * 4;
    int*   colsE   = (int*)p;   p += 1024 * 4;

    k_init<<<dim3((CC + 255) / 256), dim3(256), 0, stream>>>(W, W2, (unsigned*)bnd);
    k_csr<<<dim3(1), dim3(1024), 0, stream>>>(ar, en, offA, rowsA, offE, colsE);
    k_dp_strip<<<dim3(32), dim3(64), 0, stream>>>(W2, ar, en, alpha, beta, bnd);
    k_sub<<<dim3(256), dim3(256), 0, stream>>>(alpha, beta, W, offA, rowsA, offE, colsE, out);
    k_colpart<<<dim3(16, 8), dim3(256), 0, stream>>>(alpha, beta, cpm, cps);
    k_colfin<<<dim3(4), dim3(256), 0, stream>>>(cpm, cps, colred);
    k_ibins<<<dim3(1), dim3(256), 0, stream>>>(en, colred, W, out);
}

// Round 15
// 478.409 us; speedup vs baseline: 1.1733x; 1.1733x over previous
//
#include <hip/hip_runtime.h>

#define AA 256
#define EE 256
#define CC (AA + EE + AA*EE)   // 66048
#define TT 1024
#define VV 1024
#define NSTRIP 16
#define NCHUNKS 36             // 36 chunks x 16 supersteps = 576 supersteps
#define NEGBIG (-3.0e38f)      // finite stand-in for -inf in outputs
#define INVLN2 1.44269504088896340736f
#define LN2F   0.69314718055994530942f
#define SENT   0x7FC00001u     // NaN-payload sentinel for bnd
#define NINF   (-__builtin_inff())

#define E2(x) __builtin_amdgcn_exp2f(x)  // native v_exp_f32: 2^x
#define L2(x) __builtin_amdgcn_logf(x)   // native v_log_f32: log2(x)

__device__ __forceinline__ float safe_out(float v) {
    if (!(v > NEGBIG)) return NEGBIG;   // catches -inf, NaN
    return v;
}

__device__ __forceinline__ float lse3(float x, float y, float z) {
    float m3 = fmaxf(fmaxf(x, y), z);
    float me = __builtin_amdgcn_fmed3f(x, y, z);
    float mn = fminf(fminf(x, y), z);
    return m3 + L2(1.0f + E2(me - m3) + E2(mn - m3));
}

// ---------------- init: bnd sentinel + W2 = W/ln2 + sbuf zero ----------------
__global__ void k_init(const float* __restrict__ W, float* __restrict__ W2,
                       float* __restrict__ sbuf, unsigned* __restrict__ bndu) {
    int i = blockIdx.x * 256 + threadIdx.x;
    if (i < CC) { W2[i] = W[i] * INVLN2; sbuf[i] = 0.0f; }
    if (i < 32 * 1024) bndu[i] = SENT;
}

// ---------------- pipelined strip DP: 32 blocks x 1 wave, 2 cells/lane/superstep ----------------
// r13 core (serial 2xLSE3, proven). Changes: publish moved to CHUNK START (q=c-5)
// so the sc0sc1 publish store has ~16 ss to retire before the next poll's vmcnt(0)
// drain; boundary chunk prefetched at k==8 (waitcnt lands at next-chunk use).
__global__ __launch_bounds__(64)
void k_dp_strip(const float* __restrict__ W2, const int* __restrict__ ar,
                const int* __restrict__ en,
                float* __restrict__ alpha, float* __restrict__ beta,
                float* __restrict__ bnd) {
    __shared__ float ws_lds[256 * 64];          // [e][row], 64KB
    __shared__ float wi_s[1312];                // col = idx-128, valid 1..1023
    __shared__ int   en_s[1312];
    __shared__ float seed_s[1024];
    __shared__ float pub[2][32];                // bottom-row collect by column
    const int tid = threadIdx.x;
    const int B = blockIdx.x;                   // 0..31
    const int xcd = B & 7, slot = B >> 3;
    const int dir = xcd >> 2;
    const int b = ((xcd & 3) << 2) + slot;      // strip 0..15
    const int dirb = (dir << 4) + b;
    const bool fwd = (dir == 0);
    const bool seedstrip = (b == 0);
    const int rr = (b << 6) + tid;

    for (int x = tid; x < 1312; x += 64) {
        int col = x - 128;
        bool valid = (col >= 1 && col <= 1023);
        int e = valid ? en[fwd ? col : 1024 - col] : 0;
        en_s[x] = e;
        wi_s[x] = valid ? W2[AA + e] : 0.0f;
    }

    const int r_src = (rr >= 1) ? (fwd ? rr : (1024 - rr)) : 0;
    const float mywd2 = (rr >= 1) ? W2[ar[r_src]] : 0.0f;
    {   // stage this lane's substitution row into LDS [e][tid]
        const float* wrow = W2 + AA + EE + ((rr >= 1) ? (ar[r_src] << 8) : 0);
        #pragma unroll 8
        for (int i = 0; i < 64; ++i) {
            float4 w = *(const float4*)(wrow + (i << 2));
            ws_lds[((i << 2) + 0) * 64 + tid] = w.x;
            ws_lds[((i << 2) + 1) * 64 + tid] = w.y;
            ws_lds[((i << 2) + 2) * 64 + tid] = w.z;
            ws_lds[((i << 2) + 3) * 64 + tid] = w.w;
        }
    }

    if (seedstrip) {   // seed_s[x] = sum_{c=1..x} wi_s[128+c]
        float loc[16]; float s = 0.0f;
        #pragma unroll
        for (int i = 0; i < 16; ++i) {
            int x = (tid << 4) + i;
            float w = (x >= 1) ? wi_s[128 + x] : 0.0f;
            s += w; loc[i] = s;
        }
        float cum = s;
        for (int off = 1; off < 64; off <<= 1) {
            float tt = __shfl_up(cum, off);
            if (tid >= off) cum += tt;
        }
        float excl = cum - s;
        #pragma unroll
        for (int i = 0; i < 16; ++i) seed_s[(tid << 4) + i] = excl + loc[i];
    }
    __syncthreads();

    const int outrow = fwd ? (rr << 10) : ((1023 - rr) << 10);
    float* __restrict__ obase = fwd ? alpha : beta;
    float* __restrict__ bnd_me = bnd + (size_t)dirb * 1024;
    const float* __restrict__ bnd_prev = bnd + (size_t)(dirb - 1) * 1024;
    const bool seedlane = seedstrip && (tid == 0);

    float vA = NINF, vB = NINF, upBp = NINF;
    int2   env[8];   // en pairs, prefetched 8 supersteps ahead
    float2 wiv[4];   // wi pairs, 4 ahead
    float2 wsv[4];   // ws pairs, 4 ahead
    #pragma unroll
    for (int s = 0; s < 8; ++s) env[s] = *(const int2*)&en_s[128 + 2 * s - 2 * tid];
    #pragma unroll
    for (int s = 0; s < 4; ++s) wiv[s] = *(const float2*)&wi_s[128 + 2 * s - 2 * tid];
    #pragma unroll
    for (int s = 0; s < 4; ++s)
        wsv[s] = make_float2(ws_lds[(env[s].x << 6) + tid], ws_lds[(env[s].y << 6) + tid]);

    float bvals = NINF;
    unsigned bpend = SENT;
    if (!seedstrip)   // prefetch chunk 0
        bpend = __hip_atomic_load((const unsigned*)(bnd_prev + (tid & 31)),
                                  __ATOMIC_RELAXED, __HIP_MEMORY_SCOPE_AGENT);

    for (int c = 0; c < NCHUNKS; ++c) {
        // ---- poll at chunk start (uses prefetched value first) ----
        if (c <= 31) {
            if (seedstrip) {
                bvals = seed_s[(c << 5) + (tid & 31)];
            } else {
                const unsigned* src = (const unsigned*)(bnd_prev + (c << 5) + (tid & 31));
                unsigned x = bpend;
                while (__ballot(x != SENT) != ~0ull) {
                    __builtin_amdgcn_s_sleep(1);
                    x = __hip_atomic_load(src, __ATOMIC_RELAXED, __HIP_MEMORY_SCOPE_AGENT);
                }
                bvals = __uint_as_float(x);
            }
        }
        // ---- publish q=c-5 RIGHT AFTER poll: store gets ~16 ss to retire ----
        if (b < NSTRIP - 1 && c >= 5) {
            const int q = c - 5;
            float pv = pub[q & 1][tid & 31];
            if (tid < 32) {
                const float* dst = bnd_me + (q << 5) + tid;
                asm volatile("global_store_dword %0, %1, off sc0 sc1"
                             :: "v"(dst), "v"(__float_as_uint(pv)) : "memory");
            }
        }
        #pragma unroll
        for (int k = 0; k < 16; ++k) {
            const int S = (c << 4) + k;
            const int sd = S - tid;                  // a = 2*sd
            const bool act = ((unsigned)sd < 512u);
            float bca = __int_as_float(__builtin_amdgcn_readlane(__float_as_int(bvals), 2 * k));
            float bcb = __int_as_float(__builtin_amdgcn_readlane(__float_as_int(bvals), 2 * k + 1));
            float upA = __int_as_float(__builtin_amdgcn_update_dpp(
                __float_as_int(bca), __float_as_int(vA), 0x138, 0xF, 0xF, false));
            float upB = __int_as_float(__builtin_amdgcn_update_dpp(
                __float_as_int(bcb), __float_as_int(vB), 0x138, 0xF, 0xF, false));
            float2 wsp = wsv[k & 3];
            float2 wip = wiv[k & 3];
            // software pipelines (issue early; LDS only)
            int2   ep  = *(const int2*)&en_s[128 + 2 * S + 16 - 2 * tid];    // for S+8
            float2 win = *(const float2*)&wi_s[128 + 2 * S + 8 - 2 * tid];   // for S+4
            int2   ec  = env[(k + 4) & 7];                                   // en for S+4
            float  wsx = ws_lds[(ec.x << 6) + tid];
            float  wsy = ws_lds[(ec.y << 6) + tid];

            // boundary prefetch for next chunk (waitcnt lands at next-chunk use)
            if (k == 8 && !seedstrip && c < 31)
                bpend = __hip_atomic_load(
                    (const unsigned*)(bnd_prev + ((c + 1) << 5) + (tid & 31)),
                    __ATOMIC_RELAXED, __HIP_MEMORY_SCOPE_AGENT);

            // cell a
            float dela = mywd2 + upA;                // wd + V(r-1, a)
            float suba = wsp.x + upBp;               // ws[a] + V(r-1, a-1)
            float insa = wip.x + vB;                 // wi[a] + V(r, a-1)
            float VA = lse3(dela, suba, insa);
            VA = seedlane ? bca : VA;
            VA = act ? VA : NINF;
            // cell b = a+1
            float delb = mywd2 + upB;                // wd + V(r-1, b)
            float subb = wsp.y + upA;                // ws[b] + V(r-1, a)
            float insb = wip.y + VA;                 // wi[b] + V(r, a)
            float VB = lse3(delb, subb, insb);
            VB = seedlane ? bcb : VB;
            VB = act ? VB : NINF;

            env[(k + 8) & 7] = ep;
            wiv[(k + 4) & 3] = win;
            wsv[(k + 4) & 3] = make_float2(wsx, wsy);

            if (act) {
                const int a = 2 * sd;
                if (tid == 63)                        // bottom-row collect by column
                    *(float2*)&pub[(a >> 5) & 1][a & 31] = make_float2(VA, VB);
                if (fwd) *(float2*)(obase + outrow + a) = make_float2(VA, VB);
                else     *(float2*)(obase + outrow + (1022 - a)) = make_float2(VB, VA);
            }
            upBp = upB; vA = VA; vB = VB;
        }
    }
    // ---- tail publish: q=31 (written during chunks 34-35) ----
    if (b < NSTRIP - 1) {
        float pv = pub[1][tid & 31];
        if (tid < 32) {
            const float* dst = bnd_me + (31 << 5) + tid;
            asm volatile("global_store_dword %0, %1, off sc0 sc1"
                         :: "v"(dst), "v"(__float_as_uint(pv)) : "memory");
        }
    }
}

// ---------------- block reduce helpers (256 threads = 4 waves) ----------------
__device__ __forceinline__ float blk_max(float v, float* sm) {
    for (int off = 32; off > 0; off >>= 1) v = fmaxf(v, __shfl_xor(v, off));
    if ((threadIdx.x & 63) == 0) sm[threadIdx.x >> 6] = v;
    __syncthreads();
    float r = fmaxf(fmaxf(sm[0], sm[1]), fmaxf(sm[2], sm[3]));
    __syncthreads();
    return r;
}
__device__ __forceinline__ float blk_sum(float v, float* sm) {
    for (int off = 32; off > 0; off >>= 1) v += __shfl_xor(v, off);
    if ((threadIdx.x & 63) == 0) sm[threadIdx.x >> 6] = v;
    __syncthreads();
    float r = sm[0] + sm[1] + sm[2] + sm[3];
    __syncthreads();
    return r;
}

// ---------------- fused epilogue pass 1 ----------------
// Blocks 0..1022: row t=bi+1 -> rowred[t] + Z-rescaled sub-bin atomicAdds
// (every cell value <= Z = alpha[1023][1023], so exp2(v-Z) <= 1: no max pass).
// Blocks 1023..1150: colpart tiles (16 j-tiles x 8 t-bands).
__global__ __launch_bounds__(256)
void k_all(const float* __restrict__ alpha, const float* __restrict__ beta,
           const int* __restrict__ ar, const int* __restrict__ en,
           float* __restrict__ rowred, float* __restrict__ sbuf,
           float* __restrict__ cpm, float* __restrict__ cps) {
    const int bi = blockIdx.x;
    const int tid = threadIdx.x;
    if (bi < 1023) {
        __shared__ float als[1024];
        __shared__ float sm[4];
        const int t = bi + 1;
        const float Z2 = alpha[(size_t)1023 * 1024 + 1023];
        float al[4], bt[4];
        #pragma unroll
        for (int i = 0; i < 4; ++i) {
            int j = tid + (i << 8);
            al[i] = alpha[(size_t)(t - 1) * 1024 + j];
            bt[i] = beta[(size_t)t * 1024 + j];
            als[j] = al[i];
        }
        __syncthreads();
        float v[4]; float m = NINF;
        #pragma unroll
        for (int i = 0; i < 4; ++i) { v[i] = al[i] + bt[i]; m = fmaxf(m, v[i]); }
        m = blk_max(m, sm);
        float s = 0.0f;
        #pragma unroll
        for (int i = 0; i < 4; ++i) s += E2(v[i] - m);
        s = blk_sum(s, sm);
        if (tid == 0) rowred[t] = m + L2(s);
        const int base = AA + EE + (ar[t] << 8);
        #pragma unroll
        for (int i = 0; i < 4; ++i) {
            int j = tid + (i << 8);
            if (j >= 1)
                atomicAdd(&sbuf[base + en[j]], E2(als[j - 1] + bt[i] - Z2));
        }
    } else {
        __shared__ float smm[4][64], sms[4][64];
        int cp = bi - 1023;                 // 0..127
        int c = tid & 63;
        int g = tid >> 6;
        int j = ((cp & 15) << 6) + c;
        int t0 = (cp >> 4) << 7;
        float m = NINF, s = 0.0f;
        if (j >= 1) {
            for (int t = t0 + g; t < t0 + 128; t += 4) {
                float v = alpha[(size_t)t * 1024 + (j - 1)] + beta[(size_t)t * 1024 + j];
                if (v <= m) s += E2(v - m);
                else { s = s * E2(m - v) + 1.0f; m = v; }
            }
        }
        smm[g][c] = m; sms[g][c] = s;
        __syncthreads();
        if (g == 0) {
            float M = m, S = s;
            for (int k = 1; k < 4; ++k) {
                float mk = smm[k][c], sk = sms[k][c];
                if (mk <= M) S += sk * E2(mk - M);
                else { S = S * E2(M - mk) + sk; M = mk; }
            }
            cpm[(size_t)(cp >> 4) * 1024 + j] = M;
            cps[(size_t)(cp >> 4) * 1024 + j] = S;
        }
    }
}

// ---------------- fused epilogue pass 2 ----------------
// Blocks 0..255: sub-bin finalize. Block 256: dbins. Block 257: colfin + ibins.
__global__ __launch_bounds__(256)
void k_fin(const float* __restrict__ W, const int* __restrict__ ar,
           const int* __restrict__ en, const float* __restrict__ rowred,
           const float* __restrict__ sbuf, const float* __restrict__ cpm,
           const float* __restrict__ cps, const float* __restrict__ alpha,
           float* __restrict__ out) {
    const int blk = blockIdx.x;
    const int tid = threadIdx.x;
    if (blk < 256) {
        const float Z2 = alpha[(size_t)1023 * 1024 + 1023];
        int id = AA + EE + (blk << 8) + tid;
        float s = sbuf[id];
        out[id] = (s > 0.0f) ? safe_out(W[id] + LN2F * (Z2 + L2(s))) : NEGBIG;
        return;
    }
    if (blk == 256) {       // dbins: bin rowred by ar
        __shared__ float fv[1024]; __shared__ int iv[1024];
        for (int x = tid; x < 1024; x += 256) { fv[x] = rowred[x]; iv[x] = ar[x]; }
        __syncthreads();
        float m = NINF, s = 0.0f;
        for (int t = 1; t < 1024; ++t) {
            if (iv[t] == tid) {
                float v = fv[t];
                if (v <= m) s += E2(v - m);
                else { s = s * E2(m - v) + 1.0f; m = v; }
            }
        }
        out[tid] = (m == NINF) ? NEGBIG : safe_out(W[tid] + LN2F * (m + L2(s)));
    } else {                // colfin + ibins
        __shared__ float cr[1024]; __shared__ int ev[1024];
        for (int jj = tid; jj < 1024; jj += 256) {
            float M = NINF, S = 0.0f;
            for (int k = 0; k < 8; ++k) {
                float mk = cpm[(size_t)k * 1024 + jj], sk = cps[(size_t)k * 1024 + jj];
                if (mk <= M) S += sk * E2(mk - M);
                else { S = S * E2(M - mk) + sk; M = mk; }
            }
            cr[jj] = (jj >= 1) ? (M + L2(S)) : NINF;
            ev[jj] = en[jj];
        }
        __syncthreads();
        float m = NINF, s = 0.0f;
        for (int j = 1; j < 1024; ++j) {
            if (ev[j] == tid) {
                float v = cr[j];
                if (v <= m) s += E2(v - m);
                else { s = s * E2(m - v) + 1.0f; m = v; }
            }
        }
        out[AA + tid] = (m == NINF) ? NEGBIG : safe_out(W[AA + tid] + LN2F * (m + L2(s)));
    }
}

extern "C" void kernel_launch(void* const* d_in, const int* in_sizes, int n_in,
                              void* d_out, int out_size, void* d_ws, size_t ws_size,
                              hipStream_t stream) {
    const float* W  = (const float*)d_in[0];
    const int*   ar = (const int*)d_in[1];
    const int*   en = (const int*)d_in[2];
    float* out = (float*)d_out;

    char* p = (char*)d_ws;
    float* W2      = (float*)p; p += (size_t)CC * 4;
    float* alpha   = (float*)p; p += (size_t)TT * VV * 4;
    float* beta    = (float*)p; p += (size_t)TT * VV * 4;
    float* bnd     = (float*)p; p += (size_t)32 * 1024 * 4;
    float* rowred  = (float*)p; p += 1024 * 4;
    float* cpm     = (float*)p; p += (size_t)8 * 1024 * 4;
    float* cps     = (float*)p; p += (size_t)8 * 1024 * 4;
    float* sbuf    = (float*)p; p += (size_t)CC * 4;

    k_init<<<dim3((CC + 255) / 256), dim3(256), 0, stream>>>(W, W2, sbuf, (unsigned*)bnd);
    k_dp_strip<<<dim3(32), dim3(64), 0, stream>>>(W2, ar, en, alpha, beta, bnd);
    k_all<<<dim3(1023 + 128), dim3(256), 0, stream>>>(alpha, beta, ar, en,
                                                      rowred, sbuf, cpm, cps);
    k_fin<<<dim3(258), dim3(256), 0, stream>>>(W, ar, en, rowred, sbuf, cpm, cps,
                                               alpha, out);
}

// Round 16
// 468.265 us; speedup vs baseline: 1.1987x; 1.0217x over previous
//
#include <hip/hip_runtime.h>

#define AA 256
#define EE 256
#define CC (AA + EE + AA*EE)   // 66048
#define TT 1024
#define VV 1024
#define NSTRIP 16
#define NCHUNKS 36             // 36 chunks x 16 supersteps = 576 supersteps
#define NEGBIG (-3.0e38f)      // finite stand-in for -inf in outputs
#define INVLN2 1.44269504088896340736f
#define LN2F   0.69314718055994530942f
#define SENT   0x7FC00001u     // NaN-payload sentinel for bnd
#define NINF   (-__builtin_inff())

#define E2(x) __builtin_amdgcn_exp2f(x)  // native v_exp_f32: 2^x
#define L2(x) __builtin_amdgcn_logf(x)   // native v_log_f32: log2(x)

__device__ __forceinline__ float safe_out(float v) {
    if (!(v > NEGBIG)) return NEGBIG;   // catches -inf, NaN
    return v;
}

__device__ __forceinline__ float lse3(float x, float y, float z) {
    float m3 = fmaxf(fmaxf(x, y), z);
    float me = __builtin_amdgcn_fmed3f(x, y, z);
    float mn = fminf(fminf(x, y), z);
    return m3 + L2(1.0f + E2(me - m3) + E2(mn - m3));
}

// ---------------- init: bnd sentinel + W2 = W/ln2 + sbuf zero ----------------
__global__ void k_init(const float* __restrict__ W, float* __restrict__ W2,
                       float* __restrict__ sbuf, unsigned* __restrict__ bndu) {
    int i = blockIdx.x * 256 + threadIdx.x;
    if (i < CC) { W2[i] = W[i] * INVLN2; sbuf[i] = 0.0f; }
    if (i < 32 * 1024) bndu[i] = SENT;
}

// ---------------- pipelined strip DP: 32 blocks x 1 wave, 2 cells/lane/superstep ----------------
// r13 core. Key change: chunk outputs accumulate in REGISTERS (outA/outB double
// buffer); per chunk: poll -> publish(q=c-5, >=80ss old) -> bulk-store prev chunk
// (fire-and-forget, full chunk to retire) -> compute. Inner 16-ss loop has ZERO
// global ops; every poll's vmcnt(0) drains only 16-ss-old stores.
// Backward writes MIRRORED beta: betam[t][x] = beta[t][1023-x] (unified ascending
// store form for both directions).
__global__ __launch_bounds__(64)
void k_dp_strip(const float* __restrict__ W2, const int* __restrict__ ar,
                const int* __restrict__ en,
                float* __restrict__ alpha, float* __restrict__ betam,
                float* __restrict__ bnd) {
    __shared__ float ws_lds[256 * 64];          // [e][row], 64KB
    __shared__ float wi_s[1312];                // col = idx-128, valid 1..1023
    __shared__ int   en_s[1312];
    __shared__ float seed_s[1024];
    __shared__ float pub[2][32];                // bottom-row collect by column
    const int tid = threadIdx.x;
    const int B = blockIdx.x;                   // 0..31
    const int xcd = B & 7, slot = B >> 3;
    const int dir = xcd >> 2;
    const int b = ((xcd & 3) << 2) + slot;      // strip 0..15
    const int dirb = (dir << 4) + b;
    const bool fwd = (dir == 0);
    const bool seedstrip = (b == 0);
    const int rr = (b << 6) + tid;

    for (int x = tid; x < 1312; x += 64) {
        int col = x - 128;
        bool valid = (col >= 1 && col <= 1023);
        int e = valid ? en[fwd ? col : 1024 - col] : 0;
        en_s[x] = e;
        wi_s[x] = valid ? W2[AA + e] : 0.0f;
    }

    const int r_src = (rr >= 1) ? (fwd ? rr : (1024 - rr)) : 0;
    const float mywd2 = (rr >= 1) ? W2[ar[r_src]] : 0.0f;
    {   // stage this lane's substitution row into LDS [e][tid]
        const float* wrow = W2 + AA + EE + ((rr >= 1) ? (ar[r_src] << 8) : 0);
        #pragma unroll 8
        for (int i = 0; i < 64; ++i) {
            float4 w = *(const float4*)(wrow + (i << 2));
            ws_lds[((i << 2) + 0) * 64 + tid] = w.x;
            ws_lds[((i << 2) + 1) * 64 + tid] = w.y;
            ws_lds[((i << 2) + 2) * 64 + tid] = w.z;
            ws_lds[((i << 2) + 3) * 64 + tid] = w.w;
        }
    }

    if (seedstrip) {   // seed_s[x] = sum_{c=1..x} wi_s[128+c]
        float loc[16]; float s = 0.0f;
        #pragma unroll
        for (int i = 0; i < 16; ++i) {
            int x = (tid << 4) + i;
            float w = (x >= 1) ? wi_s[128 + x] : 0.0f;
            s += w; loc[i] = s;
        }
        float cum = s;
        for (int off = 1; off < 64; off <<= 1) {
            float tt = __shfl_up(cum, off);
            if (tid >= off) cum += tt;
        }
        float excl = cum - s;
        #pragma unroll
        for (int i = 0; i < 16; ++i) seed_s[(tid << 4) + i] = excl + loc[i];
    }
    __syncthreads();

    // unified output row base: fwd -> alpha[rr][.], bwd -> betam[1023-rr][.]
    float* __restrict__ orow0 = fwd ? (alpha + ((size_t)rr << 10))
                                    : (betam + ((size_t)(1023 - rr) << 10));
    float* __restrict__ bnd_me = bnd + (size_t)dirb * 1024;
    const float* __restrict__ bnd_prev = bnd + (size_t)(dirb - 1) * 1024;
    const bool seedlane = seedstrip && (tid == 0);

    float vA = NINF, vB = NINF, upBp = NINF;
    int2   env[8];   // en pairs, prefetched 8 supersteps ahead
    float2 wiv[4];   // wi pairs, 4 ahead
    float2 wsv[4];   // ws pairs, 4 ahead
    #pragma unroll
    for (int s = 0; s < 8; ++s) env[s] = *(const int2*)&en_s[128 + 2 * s - 2 * tid];
    #pragma unroll
    for (int s = 0; s < 4; ++s) wiv[s] = *(const float2*)&wi_s[128 + 2 * s - 2 * tid];
    #pragma unroll
    for (int s = 0; s < 4; ++s)
        wsv[s] = make_float2(ws_lds[(env[s].x << 6) + tid], ws_lds[(env[s].y << 6) + tid]);

    float bvals = NINF;
    float2 outA[16], outB[16];

    auto storeChunk = [&](const float2 (&po)[16], int cm1) {
        if (cm1 < 0) return;
        #pragma unroll
        for (int k2 = 0; k2 < 16; ++k2) {
            int sdp = (cm1 << 4) + k2 - tid;
            if ((unsigned)sdp < 512u)
                *(float2*)(orow0 + (sdp << 1)) = po[k2];
        }
    };

    auto computeChunk = [&](float2 (&oc)[16], int c) {
        #pragma unroll
        for (int k = 0; k < 16; ++k) {
            const int S = (c << 4) + k;
            const int sd = S - tid;                  // a = 2*sd
            const bool act = ((unsigned)sd < 512u);
            float bca = __int_as_float(__builtin_amdgcn_readlane(__float_as_int(bvals), 2 * k));
            float bcb = __int_as_float(__builtin_amdgcn_readlane(__float_as_int(bvals), 2 * k + 1));
            float upA = __int_as_float(__builtin_amdgcn_update_dpp(
                __float_as_int(bca), __float_as_int(vA), 0x138, 0xF, 0xF, false));
            float upB = __int_as_float(__builtin_amdgcn_update_dpp(
                __float_as_int(bcb), __float_as_int(vB), 0x138, 0xF, 0xF, false));
            float2 wsp = wsv[k & 3];
            float2 wip = wiv[k & 3];
            // software pipelines (issue early; LDS only)
            int2   ep  = *(const int2*)&en_s[128 + 2 * S + 16 - 2 * tid];    // for S+8
            float2 win = *(const float2*)&wi_s[128 + 2 * S + 8 - 2 * tid];   // for S+4
            int2   ec  = env[(k + 4) & 7];                                   // en for S+4
            float  wsx = ws_lds[(ec.x << 6) + tid];
            float  wsy = ws_lds[(ec.y << 6) + tid];

            // cell a
            float dela = mywd2 + upA;                // wd + V(r-1, a)
            float suba = wsp.x + upBp;               // ws[a] + V(r-1, a-1)
            float insa = wip.x + vB;                 // wi[a] + V(r, a-1)
            float VA = lse3(dela, suba, insa);
            VA = seedlane ? bca : VA;
            VA = act ? VA : NINF;
            // cell b = a+1
            float delb = mywd2 + upB;                // wd + V(r-1, b)
            float subb = wsp.y + upA;                // ws[b] + V(r-1, a)
            float insb = wip.y + VA;                 // wi[b] + V(r, a)
            float VB = lse3(delb, subb, insb);
            VB = seedlane ? bcb : VB;
            VB = act ? VB : NINF;

            env[(k + 8) & 7] = ep;
            wiv[(k + 4) & 3] = win;
            wsv[(k + 4) & 3] = make_float2(wsx, wsy);

            oc[k] = make_float2(VA, VB);             // register accumulation
            if (tid == 63 && act) {                  // bottom-row collect (LDS)
                const int a = 2 * sd;
                *(float2*)&pub[(a >> 5) & 1][a & 31] = make_float2(VA, VB);
            }
            upBp = upB; vA = VA; vB = VB;
        }
    };

    for (int c = 0; c < NCHUNKS; ++c) {
        // ---- poll chunk c (vmem queue holds only >=16-ss-old stores) ----
        if (c <= 31) {
            if (seedstrip) {
                bvals = seed_s[(c << 5) + (tid & 31)];
            } else {
                const float* src = bnd_prev + (c << 5) + (tid & 31);
                unsigned x;
                for (;;) {
                    asm volatile("global_load_dword %0, %1, off sc0 sc1\n\t"
                                 "s_waitcnt vmcnt(0)"
                                 : "=v"(x) : "v"(src) : "memory");
                    if (__ballot(x != SENT) == ~0ull) break;
                    __builtin_amdgcn_s_sleep(1);
                }
                bvals = __uint_as_float(x);
            }
        }
        // ---- publish q=c-5 (complete since end of chunk c-1) ----
        if (b < NSTRIP - 1 && c >= 5) {
            float pv = pub[(c + 1) & 1][tid & 31];
            if (tid < 32) {
                const float* dst = bnd_me + ((c - 5) << 5) + tid;
                asm volatile("global_store_dword %0, %1, off sc0 sc1"
                             :: "v"(dst), "v"(__float_as_uint(pv)) : "memory");
            }
        }
        // ---- bulk-store chunk c-1, then compute chunk c ----
        if ((c & 1) == 0) { storeChunk(outB, c - 1); computeChunk(outA, c); }
        else              { storeChunk(outA, c - 1); computeChunk(outB, c); }
    }
    // tail: store chunk 35 (odd -> outB); publish q=31 (slot 1)
    storeChunk(outB, NCHUNKS - 1);
    if (b < NSTRIP - 1) {
        float pv = pub[1][tid & 31];
        if (tid < 32) {
            const float* dst = bnd_me + (31 << 5) + tid;
            asm volatile("global_store_dword %0, %1, off sc0 sc1"
                         :: "v"(dst), "v"(__float_as_uint(pv)) : "memory");
        }
    }
}

// ---------------- block reduce helpers (256 threads = 4 waves) ----------------
__device__ __forceinline__ float blk_max(float v, float* sm) {
    for (int off = 32; off > 0; off >>= 1) v = fmaxf(v, __shfl_xor(v, off));
    if ((threadIdx.x & 63) == 0) sm[threadIdx.x >> 6] = v;
    __syncthreads();
    float r = fmaxf(fmaxf(sm[0], sm[1]), fmaxf(sm[2], sm[3]));
    __syncthreads();
    return r;
}
__device__ __forceinline__ float blk_sum(float v, float* sm) {
    for (int off = 32; off > 0; off >>= 1) v += __shfl_xor(v, off);
    if ((threadIdx.x & 63) == 0) sm[threadIdx.x >> 6] = v;
    __syncthreads();
    float r = sm[0] + sm[1] + sm[2] + sm[3];
    __syncthreads();
    return r;
}

// ---------------- fused epilogue pass 1 (betam = row-mirrored beta) ----------------
// Blocks 0..1022: row t=bi+1 -> rowred[t] + Z-rescaled sub-bin atomicAdds.
// Blocks 1023..1150: colpart tiles (16 j-tiles x 8 t-bands).
__global__ __launch_bounds__(256)
void k_all(const float* __restrict__ alpha, const float* __restrict__ betam,
           const int* __restrict__ ar, const int* __restrict__ en,
           float* __restrict__ rowred, float* __restrict__ sbuf,
           float* __restrict__ cpm, float* __restrict__ cps) {
    const int bi = blockIdx.x;
    const int tid = threadIdx.x;
    if (bi < 1023) {
        __shared__ float als[1024];
        __shared__ float sm[4];
        const int t = bi + 1;
        const float Z2 = alpha[(size_t)1023 * 1024 + 1023];
        float al[4], bt[4];
        #pragma unroll
        for (int i = 0; i < 4; ++i) {
            int j = tid + (i << 8);
            al[i] = alpha[(size_t)(t - 1) * 1024 + j];
            bt[i] = betam[(size_t)t * 1024 + (1023 - j)];   // beta[t][j]
            als[j] = al[i];
        }
        __syncthreads();
        float v[4]; float m = NINF;
        #pragma unroll
        for (int i = 0; i < 4; ++i) { v[i] = al[i] + bt[i]; m = fmaxf(m, v[i]); }
        m = blk_max(m, sm);
        float s = 0.0f;
        #pragma unroll
        for (int i = 0; i < 4; ++i) s += E2(v[i] - m);
        s = blk_sum(s, sm);
        if (tid == 0) rowred[t] = m + L2(s);
        const int base = AA + EE + (ar[t] << 8);
        #pragma unroll
        for (int i = 0; i < 4; ++i) {
            int j = tid + (i << 8);
            if (j >= 1)
                atomicAdd(&sbuf[base + en[j]], E2(als[j - 1] + bt[i] - Z2));
        }
    } else {
        __shared__ float smm[4][64], sms[4][64];
        int cp = bi - 1023;                 // 0..127
        int c = tid & 63;
        int g = tid >> 6;
        int j = ((cp & 15) << 6) + c;
        int t0 = (cp >> 4) << 7;
        float m = NINF, s = 0.0f;
        if (j >= 1) {
            for (int t = t0 + g; t < t0 + 128; t += 4) {
                float v = alpha[(size_t)t * 1024 + (j - 1)]
                        + betam[(size_t)t * 1024 + (1023 - j)];   // beta[t][j]
                if (v <= m) s += E2(v - m);
                else { s = s * E2(m - v) + 1.0f; m = v; }
            }
        }
        smm[g][c] = m; sms[g][c] = s;
        __syncthreads();
        if (g == 0) {
            float M = m, S = s;
            for (int k = 1; k < 4; ++k) {
                float mk = smm[k][c], sk = sms[k][c];
                if (mk <= M) S += sk * E2(mk - M);
                else { S = S * E2(M - mk) + sk; M = mk; }
            }
            cpm[(size_t)(cp >> 4) * 1024 + j] = M;
            cps[(size_t)(cp >> 4) * 1024 + j] = S;
        }
    }
}

// ---------------- fused epilogue pass 2 ----------------
// Blocks 0..255: sub-bin finalize. Block 256: dbins. Block 257: colfin + ibins.
__global__ __launch_bounds__(256)
void k_fin(const float* __restrict__ W, const int* __restrict__ ar,
           const int* __restrict__ en, const float* __restrict__ rowred,
           const float* __restrict__ sbuf, const float* __restrict__ cpm,
           const float* __restrict__ cps, const float* __restrict__ alpha,
           float* __restrict__ out) {
    const int blk = blockIdx.x;
    const int tid = threadIdx.x;
    if (blk < 256) {
        const float Z2 = alpha[(size_t)1023 * 1024 + 1023];
        int id = AA + EE + (blk << 8) + tid;
        float s = sbuf[id];
        out[id] = (s > 0.0f) ? safe_out(W[id] + LN2F * (Z2 + L2(s))) : NEGBIG;
        return;
    }
    if (blk == 256) {       // dbins: bin rowred by ar
        __shared__ float fv[1024]; __shared__ int iv[1024];
        for (int x = tid; x < 1024; x += 256) { fv[x] = rowred[x]; iv[x] = ar[x]; }
        __syncthreads();
        float m = NINF, s = 0.0f;
        for (int t = 1; t < 1024; ++t) {
            if (iv[t] == tid) {
                float v = fv[t];
                if (v <= m) s += E2(v - m);
                else { s = s * E2(m - v) + 1.0f; m = v; }
            }
        }
        out[tid] = (m == NINF) ? NEGBIG : safe_out(W[tid] + LN2F * (m + L2(s)));
    } else {                // colfin + ibins
        __shared__ float cr[1024]; __shared__ int ev[1024];
        for (int jj = tid; jj < 1024; jj += 256) {
            float M = NINF, S = 0.0f;
            for (int k = 0; k < 8; ++k) {
                float mk = cpm[(size_t)k * 1024 + jj], sk = cps[(size_t)k * 1024 + jj];
                if (mk <= M) S += sk * E2(mk - M);
                else { S = S * E2(M - mk) + sk; M = mk; }
            }
            cr[jj] = (jj >= 1) ? (M + L2(S)) : NINF;
            ev[jj] = en[jj];
        }
        __syncthreads();
        float m = NINF, s = 0.0f;
        for (int j = 1; j < 1024; ++j) {
            if (ev[j] == tid) {
                float v = cr[j];
                if (v <= m) s += E2(v - m);
                else { s = s * E2(m - v) + 1.0f; m = v; }
            }
        }
        out[AA + tid] = (m == NINF) ? NEGBIG : safe_out(W[AA + tid] + LN2F * (m + L2(s)));
    }
}

extern "C" void kernel_launch(void* const* d_in, const int* in_sizes, int n_in,
                              void* d_out, int out_size, void* d_ws, size_t ws_size,
                              hipStream_t stream) {
    const float* W  = (const float*)d_in[0];
    const int*   ar = (const int*)d_in[1];
    const int*   en = (const int*)d_in[2];
    float* out = (float*)d_out;

    char* p = (char*)d_ws;
    float* W2      = (float*)p; p += (size_t)CC * 4;
    float* alpha   = (float*)p; p += (size_t)TT * VV * 4;
    float* betam   = (float*)p; p += (size_t)TT * VV * 4;   // row-mirrored beta
    float* bnd     = (float*)p; p += (size_t)32 * 1024 * 4;
    float* rowred  = (float*)p; p += 1024 * 4;
    float* cpm     = (float*)p; p += (size_t)8 * 1024 * 4;
    float* cps     = (float*)p; p += (size_t)8 * 1024 * 4;
    float* sbuf    = (float*)p; p += (size_t)CC * 4;

    k_init<<<dim3((CC + 255) / 256), dim3(256), 0, stream>>>(W, W2, sbuf, (unsigned*)bnd);
    k_dp_strip<<<dim3(32), dim3(64), 0, stream>>>(W2, ar, en, alpha, betam, bnd);
    k_all<<<dim3(1023 + 128), dim3(256), 0, stream>>>(alpha, betam, ar, en,
                                                      rowred, sbuf, cpm, cps);
    k_fin<<<dim3(258), dim3(256), 0, stream>>>(W, ar, en, rowred, sbuf, cpm, cps,
                                               alpha, out);
}

// Round 17
// 410.697 us; speedup vs baseline: 1.3667x; 1.1402x over previous
//
#include <hip/hip_runtime.h>

#define AA 256
#define EE 256
#define CC (AA + EE + AA*EE)   // 66048
#define TT 1024
#define VV 1024
#define NSTRIP 16
#define NCHUNKS 36             // 36 chunks x 16 supersteps = 576 supersteps
#define NEGBIG (-3.0e38f)      // finite stand-in for -inf in outputs
#define INVLN2 1.44269504088896340736f
#define LN2F   0.69314718055994530942f
#define SENT   0x7FC00001u     // NaN-payload sentinel for bnd
#define NINF   (-__builtin_inff())

#define E2(x) __builtin_amdgcn_exp2f(x)  // native v_exp_f32: 2^x
#define L2(x) __builtin_amdgcn_logf(x)   // native v_log_f32: log2(x)

struct TrueT  { static constexpr bool value = true;  };
struct FalseT { static constexpr bool value = false; };

__device__ __forceinline__ float safe_out(float v) {
    if (!(v > NEGBIG)) return NEGBIG;   // catches -inf, NaN
    return v;
}

__device__ __forceinline__ float lse3(float x, float y, float z) {
    float m3 = fmaxf(fmaxf(x, y), z);
    float me = __builtin_amdgcn_fmed3f(x, y, z);
    float mn = fminf(fminf(x, y), z);
    return m3 + L2(1.0f + E2(me - m3) + E2(mn - m3));
}

// ---------------- init: bnd sentinel + sbuf zero (W2 pass folded into DP) ----------------
__global__ void k_init(float* __restrict__ sbuf, unsigned* __restrict__ bndu) {
    int i = blockIdx.x * 256 + threadIdx.x;
    if (i < CC) sbuf[i] = 0.0f;
    if (i < 32 * 1024) bndu[i] = SENT;
}

// ---------------- strip DP body (r13 core; SEED templated; act-free full chunks) ----------------
template<bool SEED>
__device__ __forceinline__ void dp_run(
        const float* __restrict__ W, const int* __restrict__ ar,
        const int* __restrict__ en,
        float* __restrict__ alpha, float* __restrict__ betam,
        float* __restrict__ bnd,
        float (&ws_lds)[256 * 64], float (&wi_s)[1312], int (&en_s)[1312],
        float (&seed_s)[1024], float (&pub)[2][32],
        int tid, int dirb, int b, bool fwd) {

    const int rr = (b << 6) + tid;

    for (int x = tid; x < 1312; x += 64) {
        int col = x - 128;
        bool valid = (col >= 1 && col <= 1023);
        int e = valid ? en[fwd ? col : 1024 - col] : 0;
        en_s[x] = e;
        wi_s[x] = valid ? W[AA + e] * INVLN2 : 0.0f;
    }

    const int r_src = (rr >= 1) ? (fwd ? rr : (1024 - rr)) : 0;
    const float mywd2 = (rr >= 1) ? W[ar[r_src]] * INVLN2 : 0.0f;
    {   // stage this lane's substitution row into LDS [e][tid] (scaled inline)
        const float* wrow = W + AA + EE + ((rr >= 1) ? (ar[r_src] << 8) : 0);
        #pragma unroll 8
        for (int i = 0; i < 64; ++i) {
            float4 w = *(const float4*)(wrow + (i << 2));
            ws_lds[((i << 2) + 0) * 64 + tid] = w.x * INVLN2;
            ws_lds[((i << 2) + 1) * 64 + tid] = w.y * INVLN2;
            ws_lds[((i << 2) + 2) * 64 + tid] = w.z * INVLN2;
            ws_lds[((i << 2) + 3) * 64 + tid] = w.w * INVLN2;
        }
    }

    if (SEED) {   // seed_s[x] = sum_{c=1..x} wi_s[128+c]
        float loc[16]; float s = 0.0f;
        #pragma unroll
        for (int i = 0; i < 16; ++i) {
            int x = (tid << 4) + i;
            float w = (x >= 1) ? wi_s[128 + x] : 0.0f;
            s += w; loc[i] = s;
        }
        float cum = s;
        for (int off = 1; off < 64; off <<= 1) {
            float tt = __shfl_up(cum, off);
            if (tid >= off) cum += tt;
        }
        float excl = cum - s;
        #pragma unroll
        for (int i = 0; i < 16; ++i) seed_s[(tid << 4) + i] = excl + loc[i];
    }
    __syncthreads();

    // unified output row base: fwd -> alpha[rr][.], bwd -> betam[1023-rr][.]
    // (betam[t][x] = beta[t][1023-x]; both directions store (VA,VB) ascending)
    float* __restrict__ orow0 = fwd ? (alpha + ((size_t)rr << 10))
                                    : (betam + ((size_t)(1023 - rr) << 10));
    float* __restrict__ bnd_me = bnd + (size_t)dirb * 1024;
    const float* __restrict__ bnd_prev = bnd + (size_t)(dirb - 1) * 1024;
    const bool seedlane = SEED && (tid == 0);

    float vA = NINF, vB = NINF, upBp = NINF;
    int2   env[8];
    float2 wiv[4];
    float2 wsv[4];
    #pragma unroll
    for (int s = 0; s < 8; ++s) env[s] = *(const int2*)&en_s[128 + 2 * s - 2 * tid];
    #pragma unroll
    for (int s = 0; s < 4; ++s) wiv[s] = *(const float2*)&wi_s[128 + 2 * s - 2 * tid];
    #pragma unroll
    for (int s = 0; s < 4; ++s)
        wsv[s] = make_float2(ws_lds[(env[s].x << 6) + tid], ws_lds[(env[s].y << 6) + tid]);

    float bvals = NINF;

    auto body = [&](int c, int k, auto FULL_) {
        constexpr bool FULL = decltype(FULL_)::value;
        const int S = (c << 4) + k;
        const int sd = S - tid;                  // a = 2*sd
        const bool act = FULL || ((unsigned)sd < 512u);
        float bca = __int_as_float(__builtin_amdgcn_readlane(__float_as_int(bvals), 2 * k));
        float bcb = __int_as_float(__builtin_amdgcn_readlane(__float_as_int(bvals), 2 * k + 1));
        float upA = __int_as_float(__builtin_amdgcn_update_dpp(
            __float_as_int(bca), __float_as_int(vA), 0x138, 0xF, 0xF, false));
        float upB = __int_as_float(__builtin_amdgcn_update_dpp(
            __float_as_int(bcb), __float_as_int(vB), 0x138, 0xF, 0xF, false));
        float2 wsp = wsv[k & 3];
        float2 wip = wiv[k & 3];
        // software pipelines (issue early; LDS only)
        int2   ep  = *(const int2*)&en_s[128 + 2 * S + 16 - 2 * tid];    // for S+8
        float2 win = *(const float2*)&wi_s[128 + 2 * S + 8 - 2 * tid];   // for S+4
        int2   ec  = env[(k + 4) & 7];                                   // en for S+4
        float  wsx = ws_lds[(ec.x << 6) + tid];
        float  wsy = ws_lds[(ec.y << 6) + tid];

        // cell a
        float dela = mywd2 + upA;
        float suba = wsp.x + upBp;
        float insa = wip.x + vB;
        float VA = lse3(dela, suba, insa);
        if (SEED) VA = seedlane ? bca : VA;
        if (!FULL) VA = act ? VA : NINF;
        // cell b = a+1
        float delb = mywd2 + upB;
        float subb = wsp.y + upA;
        float insb = wip.y + VA;
        float VB = lse3(delb, subb, insb);
        if (SEED) VB = seedlane ? bcb : VB;
        if (!FULL) VB = act ? VB : NINF;

        env[(k + 8) & 7] = ep;
        wiv[(k + 4) & 3] = win;
        wsv[(k + 4) & 3] = make_float2(wsx, wsy);

        if (act) {
            const int a = 2 * sd;
            if (tid == 63)                        // bottom-row collect by column
                *(float2*)&pub[(a >> 5) & 1][a & 31] = make_float2(VA, VB);
            *(float2*)(orow0 + (sd << 1)) = make_float2(VA, VB);
        }
        upBp = upB; vA = VA; vB = VB;
    };

    for (int c = 0; c < NCHUNKS; ++c) {
        // ---- fetch boundary cols 32c..32c+31 (consumer) ----
        if (c <= 31) {
            if (SEED) {
                bvals = seed_s[(c << 5) + (tid & 31)];
            } else {
                const float* src = bnd_prev + (c << 5) + (tid & 31);
                unsigned x;
                for (;;) {
                    asm volatile("global_load_dword %0, %1, off sc0 sc1\n\t"
                                 "s_waitcnt vmcnt(0)"
                                 : "=v"(x) : "v"(src) : "memory");
                    if (__ballot(x != SENT) == ~0ull) break;
                    __builtin_amdgcn_s_sleep(1);
                }
                bvals = __uint_as_float(x);
            }
        }
        if (c >= 4 && c <= 31) {                  // all lanes active: act-free body
            #pragma unroll
            for (int k = 0; k < 16; ++k) body(c, k, TrueT{});
        } else {
            #pragma unroll
            for (int k = 0; k < 16; ++k) body(c, k, FalseT{});
        }
        // ---- publish col-chunk q=c-4 (complete as of superstep 16c+15) ----
        if (b < NSTRIP - 1 && c >= 4) {
            const int q = c - 4;
            float pv = pub[q & 1][tid & 31];
            if (tid < 32) {
                const float* dst = bnd_me + (q << 5) + tid;
                asm volatile("global_store_dword %0, %1, off sc0 sc1"
                             :: "v"(dst), "v"(__float_as_uint(pv)) : "memory");
            }
        }
    }
}

__global__ __launch_bounds__(64)
void k_dp_strip(const float* __restrict__ W, const int* __restrict__ ar,
                const int* __restrict__ en,
                float* __restrict__ alpha, float* __restrict__ betam,
                float* __restrict__ bnd) {
    __shared__ float ws_lds[256 * 64];          // [e][row], 64KB
    __shared__ float wi_s[1312];
    __shared__ int   en_s[1312];
    __shared__ float seed_s[1024];
    __shared__ float pub[2][32];
    const int tid = threadIdx.x;
    const int B = blockIdx.x;                   // 0..31
    const int xcd = B & 7, slot = B >> 3;
    const int dir = xcd >> 2;
    const int b = ((xcd & 3) << 2) + slot;      // strip 0..15
    const int dirb = (dir << 4) + b;
    const bool fwd = (dir == 0);
    if (b == 0)
        dp_run<true >(W, ar, en, alpha, betam, bnd, ws_lds, wi_s, en_s, seed_s, pub,
                      tid, dirb, b, fwd);
    else
        dp_run<false>(W, ar, en, alpha, betam, bnd, ws_lds, wi_s, en_s, seed_s, pub,
                      tid, dirb, b, fwd);
}

// ---------------- block reduce helpers (256 threads = 4 waves) ----------------
__device__ __forceinline__ float blk_max(float v, float* sm) {
    for (int off = 32; off > 0; off >>= 1) v = fmaxf(v, __shfl_xor(v, off));
    if ((threadIdx.x & 63) == 0) sm[threadIdx.x >> 6] = v;
    __syncthreads();
    float r = fmaxf(fmaxf(sm[0], sm[1]), fmaxf(sm[2], sm[3]));
    __syncthreads();
    return r;
}
__device__ __forceinline__ float blk_sum(float v, float* sm) {
    for (int off = 32; off > 0; off >>= 1) v += __shfl_xor(v, off);
    if ((threadIdx.x & 63) == 0) sm[threadIdx.x >> 6] = v;
    __syncthreads();
    float r = sm[0] + sm[1] + sm[2] + sm[3];
    __syncthreads();
    return r;
}

// ---------------- fused epilogue pass 1 (betam = row-mirrored beta) ----------------
__global__ __launch_bounds__(256)
void k_all(const float* __restrict__ alpha, const float* __restrict__ betam,
           const int* __restrict__ ar, const int* __restrict__ en,
           float* __restrict__ rowred, float* __restrict__ sbuf,
           float* __restrict__ cpm, float* __restrict__ cps) {
    const int bi = blockIdx.x;
    const int tid = threadIdx.x;
    if (bi < 1023) {
        __shared__ float als[1024];
        __shared__ float sm[4];
        const int t = bi + 1;
        const float Z2 = alpha[(size_t)1023 * 1024 + 1023];
        float al[4], bt[4];
        #pragma unroll
        for (int i = 0; i < 4; ++i) {
            int j = tid + (i << 8);
            al[i] = alpha[(size_t)(t - 1) * 1024 + j];
            bt[i] = betam[(size_t)t * 1024 + (1023 - j)];   // beta[t][j]
            als[j] = al[i];
        }
        __syncthreads();
        float v[4]; float m = NINF;
        #pragma unroll
        for (int i = 0; i < 4; ++i) { v[i] = al[i] + bt[i]; m = fmaxf(m, v[i]); }
        m = blk_max(m, sm);
        float s = 0.0f;
        #pragma unroll
        for (int i = 0; i < 4; ++i) s += E2(v[i] - m);
        s = blk_sum(s, sm);
        if (tid == 0) rowred[t] = m + L2(s);
        const int base = AA + EE + (ar[t] << 8);
        #pragma unroll
        for (int i = 0; i < 4; ++i) {
            int j = tid + (i << 8);
            if (j >= 1)
                atomicAdd(&sbuf[base + en[j]], E2(als[j - 1] + bt[i] - Z2));
        }
    } else {
        __shared__ float smm[4][64], sms[4][64];
        int cp = bi - 1023;                 // 0..127
        int c = tid & 63;
        int g = tid >> 6;
        int j = ((cp & 15) << 6) + c;
        int t0 = (cp >> 4) << 7;
        float m = NINF, s = 0.0f;
        if (j >= 1) {
            for (int t = t0 + g; t < t0 + 128; t += 4) {
                float v = alpha[(size_t)t * 1024 + (j - 1)]
                        + betam[(size_t)t * 1024 + (1023 - j)];   // beta[t][j]
                if (v <= m) s += E2(v - m);
                else { s = s * E2(m - v) + 1.0f; m = v; }
            }
        }
        smm[g][c] = m; sms[g][c] = s;
        __syncthreads();
        if (g == 0) {
            float M = m, S = s;
            for (int k = 1; k < 4; ++k) {
                float mk = smm[k][c], sk = sms[k][c];
                if (mk <= M) S += sk * E2(mk - M);
                else { S = S * E2(M - mk) + sk; M = mk; }
            }
            cpm[(size_t)(cp >> 4) * 1024 + j] = M;
            cps[(size_t)(cp >> 4) * 1024 + j] = S;
        }
    }
}

// ---------------- fused epilogue pass 2 ----------------
__global__ __launch_bounds__(256)
void k_fin(const float* __restrict__ W, const int* __restrict__ ar,
           const int* __restrict__ en, const float* __restrict__ rowred,
           const float* __restrict__ sbuf, const float* __restrict__ cpm,
           const float* __restrict__ cps, const float* __restrict__ alpha,
           float* __restrict__ out) {
    const int blk = blockIdx.x;
    const int tid = threadIdx.x;
    if (blk < 256) {
        const float Z2 = alpha[(size_t)1023 * 1024 + 1023];
        int id = AA + EE + (blk << 8) + tid;
        float s = sbuf[id];
        out[id] = (s > 0.0f) ? safe_out(W[id] + LN2F * (Z2 + L2(s))) : NEGBIG;
        return;
    }
    if (blk == 256) {       // dbins: bin rowred by ar
        __shared__ float fv[1024]; __shared__ int iv[1024];
        for (int x = tid; x < 1024; x += 256) { fv[x] = rowred[x]; iv[x] = ar[x]; }
        __syncthreads();
        float m = NINF, s = 0.0f;
        for (int t = 1; t < 1024; ++t) {
            if (iv[t] == tid) {
                float v = fv[t];
                if (v <= m) s += E2(v - m);
                else { s = s * E2(m - v) + 1.0f; m = v; }
            }
        }
        out[tid] = (m == NINF) ? NEGBIG : safe_out(W[tid] + LN2F * (m + L2(s)));
    } else {                // colfin + ibins
        __shared__ float cr[1024]; __shared__ int ev[1024];
        for (int jj = tid; jj < 1024; jj += 256) {
            float M = NINF, S = 0.0f;
            for (int k = 0; k < 8; ++k) {
                float mk = cpm[(size_t)k * 1024 + jj], sk = cps[(size_t)k * 1024 + jj];
                if (mk <= M) S += sk * E2(mk - M);
                else { S = S * E2(M - mk) + sk; M = mk; }
            }
            cr[jj] = (jj >= 1) ? (M + L2(S)) : NINF;
            ev[jj] = en[jj];
        }
        __syncthreads();
        float m = NINF, s = 0.0f;
        for (int j = 1; j < 1024; ++j) {
            if (ev[j] == tid) {
                float v = cr[j];
                if (v <= m) s += E2(v - m);
                else { s = s * E2(m - v) + 1.0f; m = v; }
            }
        }
        out[AA + tid] = (m == NINF) ? NEGBIG : safe_out(W[AA + tid] + LN2F * (m + L2(s)));
    }
}

extern "C" void kernel_launch(void* const* d_in, const int* in_sizes, int n_in,
                              void* d_out, int out_size, void* d_ws, size_t ws_size,
                              hipStream_t stream) {
    const float* W  = (const float*)d_in[0];
    const int*   ar = (const int*)d_in[1];
    const int*   en = (const int*)d_in[2];
    float* out = (float*)d_out;

    char* p = (char*)d_ws;
    float* alpha   = (float*)p; p += (size_t)TT * VV * 4;
    float* betam   = (float*)p; p += (size_t)TT * VV * 4;   // row-mirrored beta
    float* bnd     = (float*)p; p += (size_t)32 * 1024 * 4;
    float* rowred  = (float*)p; p += 1024 * 4;
    float* cpm     = (float*)p; p += (size_t)8 * 1024 * 4;
    float* cps     = (float*)p; p += (size_t)8 * 1024 * 4;
    float* sbuf    = (float*)p; p += (size_t)CC * 4;

    k_init<<<dim3((CC + 255) / 256), dim3(256), 0, stream>>>(sbuf, (unsigned*)bnd);
    k_dp_strip<<<dim3(32), dim3(64), 0, stream>>>(W, ar, en, alpha, betam, bnd);
    k_all<<<dim3(1023 + 128), dim3(256), 0, stream>>>(alpha, betam, ar, en,
                                                      rowred, sbuf, cpm, cps);
    k_fin<<<dim3(258), dim3(256), 0, stream>>>(W, ar, en, rowred, sbuf, cpm, cps,
                                               alpha, out);
}

// Round 18
// 390.437 us; speedup vs baseline: 1.4376x; 1.0519x over previous
//
#include <hip/hip_runtime.h>

#define AA 256
#define EE 256
#define CC (AA + EE + AA*EE)   // 66048
#define TT 1024
#define VV 1024
#define NSTRIP 16
#define NCHUNKS 36             // 36 chunks x 16 supersteps = 576 supersteps
#define NEGBIG (-3.0e38f)      // finite stand-in for -inf in outputs
#define INVLN2 1.44269504088896340736f
#define LN2F   0.69314718055994530942f
#define SENT   0x7FC00001u     // NaN-payload sentinel for bnd
#define NINF   (-__builtin_inff())

#define E2(x) __builtin_amdgcn_exp2f(x)  // native v_exp_f32: 2^x
#define L2(x) __builtin_amdgcn_logf(x)   // native v_log_f32: log2(x)

struct TrueT  { static constexpr bool value = true;  };
struct FalseT { static constexpr bool value = false; };

__device__ __forceinline__ float safe_out(float v) {
    if (!(v > NEGBIG)) return NEGBIG;   // catches -inf, NaN
    return v;
}

__device__ __forceinline__ float lse3(float x, float y, float z) {
    float m3 = fmaxf(fmaxf(x, y), z);
    float me = __builtin_amdgcn_fmed3f(x, y, z);
    float mn = fminf(fminf(x, y), z);
    return m3 + L2(1.0f + E2(me - m3) + E2(mn - m3));
}

// ---------------- init: bnd sentinel + sbuf zero ----------------
__global__ void k_init(float* __restrict__ sbuf, unsigned* __restrict__ bndu) {
    int i = blockIdx.x * 256 + threadIdx.x;
    if (i < CC) sbuf[i] = 0.0f;
    if (i < 32 * 1024) bndu[i] = SENT;
}

// ---------------- strip DP body (r17, FROZEN) ----------------
template<bool SEED>
__device__ __forceinline__ void dp_run(
        const float* __restrict__ W, const int* __restrict__ ar,
        const int* __restrict__ en,
        float* __restrict__ alpha, float* __restrict__ betam,
        float* __restrict__ bnd,
        float (&ws_lds)[256 * 64], float (&wi_s)[1312], int (&en_s)[1312],
        float (&seed_s)[1024], float (&pub)[2][32],
        int tid, int dirb, int b, bool fwd) {

    const int rr = (b << 6) + tid;

    for (int x = tid; x < 1312; x += 64) {
        int col = x - 128;
        bool valid = (col >= 1 && col <= 1023);
        int e = valid ? en[fwd ? col : 1024 - col] : 0;
        en_s[x] = e;
        wi_s[x] = valid ? W[AA + e] * INVLN2 : 0.0f;
    }

    const int r_src = (rr >= 1) ? (fwd ? rr : (1024 - rr)) : 0;
    const float mywd2 = (rr >= 1) ? W[ar[r_src]] * INVLN2 : 0.0f;
    {   // stage this lane's substitution row into LDS [e][tid] (scaled inline)
        const float* wrow = W + AA + EE + ((rr >= 1) ? (ar[r_src] << 8) : 0);
        #pragma unroll 8
        for (int i = 0; i < 64; ++i) {
            float4 w = *(const float4*)(wrow + (i << 2));
            ws_lds[((i << 2) + 0) * 64 + tid] = w.x * INVLN2;
            ws_lds[((i << 2) + 1) * 64 + tid] = w.y * INVLN2;
            ws_lds[((i << 2) + 2) * 64 + tid] = w.z * INVLN2;
            ws_lds[((i << 2) + 3) * 64 + tid] = w.w * INVLN2;
        }
    }

    if (SEED) {   // seed_s[x] = sum_{c=1..x} wi_s[128+c]
        float loc[16]; float s = 0.0f;
        #pragma unroll
        for (int i = 0; i < 16; ++i) {
            int x = (tid << 4) + i;
            float w = (x >= 1) ? wi_s[128 + x] : 0.0f;
            s += w; loc[i] = s;
        }
        float cum = s;
        for (int off = 1; off < 64; off <<= 1) {
            float tt = __shfl_up(cum, off);
            if (tid >= off) cum += tt;
        }
        float excl = cum - s;
        #pragma unroll
        for (int i = 0; i < 16; ++i) seed_s[(tid << 4) + i] = excl + loc[i];
    }
    __syncthreads();

    float* __restrict__ orow0 = fwd ? (alpha + ((size_t)rr << 10))
                                    : (betam + ((size_t)(1023 - rr) << 10));
    float* __restrict__ bnd_me = bnd + (size_t)dirb * 1024;
    const float* __restrict__ bnd_prev = bnd + (size_t)(dirb - 1) * 1024;
    const bool seedlane = SEED && (tid == 0);

    float vA = NINF, vB = NINF, upBp = NINF;
    int2   env[8];
    float2 wiv[4];
    float2 wsv[4];
    #pragma unroll
    for (int s = 0; s < 8; ++s) env[s] = *(const int2*)&en_s[128 + 2 * s - 2 * tid];
    #pragma unroll
    for (int s = 0; s < 4; ++s) wiv[s] = *(const float2*)&wi_s[128 + 2 * s - 2 * tid];
    #pragma unroll
    for (int s = 0; s < 4; ++s)
        wsv[s] = make_float2(ws_lds[(env[s].x << 6) + tid], ws_lds[(env[s].y << 6) + tid]);

    float bvals = NINF;

    auto body = [&](int c, int k, auto FULL_) {
        constexpr bool FULL = decltype(FULL_)::value;
        const int S = (c << 4) + k;
        const int sd = S - tid;                  // a = 2*sd
        const bool act = FULL || ((unsigned)sd < 512u);
        float bca = __int_as_float(__builtin_amdgcn_readlane(__float_as_int(bvals), 2 * k));
        float bcb = __int_as_float(__builtin_amdgcn_readlane(__float_as_int(bvals), 2 * k + 1));
        float upA = __int_as_float(__builtin_amdgcn_update_dpp(
            __float_as_int(bca), __float_as_int(vA), 0x138, 0xF, 0xF, false));
        float upB = __int_as_float(__builtin_amdgcn_update_dpp(
            __float_as_int(bcb), __float_as_int(vB), 0x138, 0xF, 0xF, false));
        float2 wsp = wsv[k & 3];
        float2 wip = wiv[k & 3];
        int2   ep  = *(const int2*)&en_s[128 + 2 * S + 16 - 2 * tid];    // for S+8
        float2 win = *(const float2*)&wi_s[128 + 2 * S + 8 - 2 * tid];   // for S+4
        int2   ec  = env[(k + 4) & 7];                                   // en for S+4
        float  wsx = ws_lds[(ec.x << 6) + tid];
        float  wsy = ws_lds[(ec.y << 6) + tid];

        // cell a
        float dela = mywd2 + upA;
        float suba = wsp.x + upBp;
        float insa = wip.x + vB;
        float VA = lse3(dela, suba, insa);
        if (SEED) VA = seedlane ? bca : VA;
        if (!FULL) VA = act ? VA : NINF;
        // cell b = a+1
        float delb = mywd2 + upB;
        float subb = wsp.y + upA;
        float insb = wip.y + VA;
        float VB = lse3(delb, subb, insb);
        if (SEED) VB = seedlane ? bcb : VB;
        if (!FULL) VB = act ? VB : NINF;

        env[(k + 8) & 7] = ep;
        wiv[(k + 4) & 3] = win;
        wsv[(k + 4) & 3] = make_float2(wsx, wsy);

        if (act) {
            const int a = 2 * sd;
            if (tid == 63)
                *(float2*)&pub[(a >> 5) & 1][a & 31] = make_float2(VA, VB);
            *(float2*)(orow0 + (sd << 1)) = make_float2(VA, VB);
        }
        upBp = upB; vA = VA; vB = VB;
    };

    for (int c = 0; c < NCHUNKS; ++c) {
        if (c <= 31) {
            if (SEED) {
                bvals = seed_s[(c << 5) + (tid & 31)];
            } else {
                const float* src = bnd_prev + (c << 5) + (tid & 31);
                unsigned x;
                for (;;) {
                    asm volatile("global_load_dword %0, %1, off sc0 sc1\n\t"
                                 "s_waitcnt vmcnt(0)"
                                 : "=v"(x) : "v"(src) : "memory");
                    if (__ballot(x != SENT) == ~0ull) break;
                    __builtin_amdgcn_s_sleep(1);
                }
                bvals = __uint_as_float(x);
            }
        }
        if (c >= 4 && c <= 31) {
            #pragma unroll
            for (int k = 0; k < 16; ++k) body(c, k, TrueT{});
        } else {
            #pragma unroll
            for (int k = 0; k < 16; ++k) body(c, k, FalseT{});
        }
        if (b < NSTRIP - 1 && c >= 4) {
            const int q = c - 4;
            float pv = pub[q & 1][tid & 31];
            if (tid < 32) {
                const float* dst = bnd_me + (q << 5) + tid;
                asm volatile("global_store_dword %0, %1, off sc0 sc1"
                             :: "v"(dst), "v"(__float_as_uint(pv)) : "memory");
            }
        }
    }
}

__global__ __launch_bounds__(64)
void k_dp_strip(const float* __restrict__ W, const int* __restrict__ ar,
                const int* __restrict__ en,
                float* __restrict__ alpha, float* __restrict__ betam,
                float* __restrict__ bnd) {
    __shared__ float ws_lds[256 * 64];          // [e][row], 64KB
    __shared__ float wi_s[1312];
    __shared__ int   en_s[1312];
    __shared__ float seed_s[1024];
    __shared__ float pub[2][32];
    const int tid = threadIdx.x;
    const int B = blockIdx.x;                   // 0..31
    const int xcd = B & 7, slot = B >> 3;
    const int dir = xcd >> 2;
    const int b = ((xcd & 3) << 2) + slot;      // strip 0..15
    const int dirb = (dir << 4) + b;
    const bool fwd = (dir == 0);
    if (b == 0)
        dp_run<true >(W, ar, en, alpha, betam, bnd, ws_lds, wi_s, en_s, seed_s, pub,
                      tid, dirb, b, fwd);
    else
        dp_run<false>(W, ar, en, alpha, betam, bnd, ws_lds, wi_s, en_s, seed_s, pub,
                      tid, dirb, b, fwd);
}

// ---------------- block reduce helpers (256 threads = 4 waves) ----------------
__device__ __forceinline__ float blk_max(float v, float* sm) {
    for (int off = 32; off > 0; off >>= 1) v = fmaxf(v, __shfl_xor(v, off));
    if ((threadIdx.x & 63) == 0) sm[threadIdx.x >> 6] = v;
    __syncthreads();
    float r = fmaxf(fmaxf(sm[0], sm[1]), fmaxf(sm[2], sm[3]));
    __syncthreads();
    return r;
}
__device__ __forceinline__ float blk_sum(float v, float* sm) {
    for (int off = 32; off > 0; off >>= 1) v += __shfl_xor(v, off);
    if ((threadIdx.x & 63) == 0) sm[threadIdx.x >> 6] = v;
    __syncthreads();
    float r = sm[0] + sm[1] + sm[2] + sm[3];
    __syncthreads();
    return r;
}

// ---------------- fused epilogue pass 1 ----------------
// Blocks 0..1022: row t=bi+1 -> rowred[t]; sub contributions binned in LDS by e
// (row shares a=ar[t]!), ONE global atomicAdd per e per block (262K vs 1M).
// Blocks 1023..1150: colpart tiles.
__global__ __launch_bounds__(256)
void k_all(const float* __restrict__ alpha, const float* __restrict__ betam,
           const int* __restrict__ ar, const int* __restrict__ en,
           float* __restrict__ rowred, float* __restrict__ sbuf,
           float* __restrict__ cpm, float* __restrict__ cps) {
    const int bi = blockIdx.x;
    const int tid = threadIdx.x;
    if (bi < 1023) {
        __shared__ float als[1024];
        __shared__ float ebins[256];
        __shared__ float sm[4];
        const int t = bi + 1;
        const float Z2 = alpha[(size_t)1023 * 1024 + 1023];
        ebins[tid] = 0.0f;
        float al[4], bt[4];
        #pragma unroll
        for (int i = 0; i < 4; ++i) {
            int j = tid + (i << 8);
            al[i] = alpha[(size_t)(t - 1) * 1024 + j];
            bt[i] = betam[(size_t)t * 1024 + (1023 - j)];   // beta[t][j]
            als[j] = al[i];
        }
        __syncthreads();
        float v[4]; float m = NINF;
        #pragma unroll
        for (int i = 0; i < 4; ++i) { v[i] = al[i] + bt[i]; m = fmaxf(m, v[i]); }
        m = blk_max(m, sm);
        float s = 0.0f;
        #pragma unroll
        for (int i = 0; i < 4; ++i) s += E2(v[i] - m);
        s = blk_sum(s, sm);
        if (tid == 0) rowred[t] = m + L2(s);
        // sub contributions -> LDS e-bins (ds_add_f32, low contention)
        #pragma unroll
        for (int i = 0; i < 4; ++i) {
            int j = tid + (i << 8);
            if (j >= 1)
                atomicAdd(&ebins[en[j]], E2(als[j - 1] + bt[i] - Z2));
        }
        __syncthreads();
        atomicAdd(&sbuf[AA + EE + (ar[t] << 8) + tid], ebins[tid]);
    } else {
        __shared__ float smm[4][64], sms[4][64];
        int cp = bi - 1023;                 // 0..127
        int c = tid & 63;
        int g = tid >> 6;
        int j = ((cp & 15) << 6) + c;
        int t0 = (cp >> 4) << 7;
        float m = NINF, s = 0.0f;
        if (j >= 1) {
            for (int t = t0 + g; t < t0 + 128; t += 4) {
                float v = alpha[(size_t)t * 1024 + (j - 1)]
                        + betam[(size_t)t * 1024 + (1023 - j)];   // beta[t][j]
                if (v <= m) s += E2(v - m);
                else { s = s * E2(m - v) + 1.0f; m = v; }
            }
        }
        smm[g][c] = m; sms[g][c] = s;
        __syncthreads();
        if (g == 0) {
            float M = m, S = s;
            for (int k = 1; k < 4; ++k) {
                float mk = smm[k][c], sk = sms[k][c];
                if (mk <= M) S += sk * E2(mk - M);
                else { S = S * E2(M - mk) + sk; M = mk; }
            }
            cpm[(size_t)(cp >> 4) * 1024 + j] = M;
            cps[(size_t)(cp >> 4) * 1024 + j] = S;
        }
    }
}

// ---------------- fused epilogue pass 2 ----------------
__global__ __launch_bounds__(256)
void k_fin(const float* __restrict__ W, const int* __restrict__ ar,
           const int* __restrict__ en, const float* __restrict__ rowred,
           const float* __restrict__ sbuf, const float* __restrict__ cpm,
           const float* __restrict__ cps, const float* __restrict__ alpha,
           float* __restrict__ out) {
    const int blk = blockIdx.x;
    const int tid = threadIdx.x;
    if (blk < 256) {
        const float Z2 = alpha[(size_t)1023 * 1024 + 1023];
        int id = AA + EE + (blk << 8) + tid;
        float s = sbuf[id];
        out[id] = (s > 0.0f) ? safe_out(W[id] + LN2F * (Z2 + L2(s))) : NEGBIG;
        return;
    }
    if (blk == 256) {       // dbins: bin rowred by ar
        __shared__ float fv[1024]; __shared__ int iv[1024];
        for (int x = tid; x < 1024; x += 256) { fv[x] = rowred[x]; iv[x] = ar[x]; }
        __syncthreads();
        float m = NINF, s = 0.0f;
        for (int t = 1; t < 1024; ++t) {
            if (iv[t] == tid) {
                float v = fv[t];
                if (v <= m) s += E2(v - m);
                else { s = s * E2(m - v) + 1.0f; m = v; }
            }
        }
        out[tid] = (m == NINF) ? NEGBIG : safe_out(W[tid] + LN2F * (m + L2(s)));
    } else {                // colfin + ibins
        __shared__ float cr[1024]; __shared__ int ev[1024];
        for (int jj = tid; jj < 1024; jj += 256) {
            float M = NINF, S = 0.0f;
            for (int k = 0; k < 8; ++k) {
                float mk = cpm[(size_t)k * 1024 + jj], sk = cps[(size_t)k * 1024 + jj];
                if (mk <= M) S += sk * E2(mk - M);
                else { S = S * E2(M - mk) + sk; M = mk; }
            }
            cr[jj] = (jj >= 1) ? (M + L2(S)) : NINF;
            ev[jj] = en[jj];
        }
        __syncthreads();
        float m = NINF, s = 0.0f;
        for (int j = 1; j < 1024; ++j) {
            if (ev[j] == tid) {
                float v = cr[j];
                if (v <= m) s += E2(v - m);
                else { s = s * E2(m - v) + 1.0f; m = v; }
            }
        }
        out[AA + tid] = (m == NINF) ? NEGBIG : safe_out(W[AA + tid] + LN2F * (m + L2(s)));
    }
}

extern "C" void kernel_launch(void* const* d_in, const int* in_sizes, int n_in,
                              void* d_out, int out_size, void* d_ws, size_t ws_size,
                              hipStream_t stream) {
    const float* W  = (const float*)d_in[0];
    const int*   ar = (const int*)d_in[1];
    const int*   en = (const int*)d_in[2];
    float* out = (float*)d_out;

    char* p = (char*)d_ws;
    float* alpha   = (float*)p; p += (size_t)TT * VV * 4;
    float* betam   = (float*)p; p += (size_t)TT * VV * 4;   // row-mirrored beta
    float* bnd     = (float*)p; p += (size_t)32 * 1024 * 4;
    float* rowred  = (float*)p; p += 1024 * 4;
    float* cpm     = (float*)p; p += (size_t)8 * 1024 * 4;
    float* cps     = (float*)p; p += (size_t)8 * 1024 * 4;
    float* sbuf    = (float*)p; p += (size_t)CC * 4;

    k_init<<<dim3((CC + 255) / 256), dim3(256), 0, stream>>>(sbuf, (unsigned*)bnd);
    k_dp_strip<<<dim3(32), dim3(64), 0, stream>>>(W, ar, en, alpha, betam, bnd);
    k_all<<<dim3(1023 + 128), dim3(256), 0, stream>>>(alpha, betam, ar, en,
                                                      rowred, sbuf, cpm, cps);
    k_fin<<<dim3(258), dim3(256), 0, stream>>>(W, ar, en, rowred, sbuf, cpm, cps,
                                               alpha, out);
}

// Round 19
// 372.287 us; speedup vs baseline: 1.5077x; 1.0488x over previous
//
#include <hip/hip_runtime.h>

#define AA 256
#define EE 256
#define CC (AA + EE + AA*EE)   // 66048
#define TT 1024
#define VV 1024
#define NSTRIP 16
#define NCHUNKS 36             // 36 chunks x 16 supersteps = 576 supersteps
#define NEGBIG (-3.0e38f)      // finite stand-in for -inf in outputs
#define INVLN2 1.44269504088896340736f
#define LN2F   0.69314718055994530942f
#define SENT   0x7FC00001u     // NaN-payload sentinel for bnd
#define NINF   (-__builtin_inff())

#define E2(x) __builtin_amdgcn_exp2f(x)  // native v_exp_f32: 2^x
#define L2(x) __builtin_amdgcn_logf(x)   // native v_log_f32: log2(x)

struct TrueT  { static constexpr bool value = true;  };
struct FalseT { static constexpr bool value = false; };

__device__ __forceinline__ float safe_out(float v) {
    if (!(v > NEGBIG)) return NEGBIG;   // catches -inf, NaN
    return v;
}

__device__ __forceinline__ float lse3(float x, float y, float z) {
    float m3 = fmaxf(fmaxf(x, y), z);
    float me = __builtin_amdgcn_fmed3f(x, y, z);
    float mn = fminf(fminf(x, y), z);
    return m3 + L2(1.0f + E2(me - m3) + E2(mn - m3));
}

// ---------------- init: bnd sentinel + sbuf zero ----------------
__global__ void k_init(float* __restrict__ sbuf, unsigned* __restrict__ bndu) {
    int i = blockIdx.x * 256 + threadIdx.x;
    if (i < CC) sbuf[i] = 0.0f;
    if (i < 32 * 1024) bndu[i] = SENT;
}

// ---------------- strip DP body (r17, FROZEN) ----------------
template<bool SEED>
__device__ __forceinline__ void dp_run(
        const float* __restrict__ W, const int* __restrict__ ar,
        const int* __restrict__ en,
        float* __restrict__ alpha, float* __restrict__ betam,
        float* __restrict__ bnd,
        float (&ws_lds)[256 * 64], float (&wi_s)[1312], int (&en_s)[1312],
        float (&seed_s)[1024], float (&pub)[2][32],
        int tid, int dirb, int b, bool fwd) {

    const int rr = (b << 6) + tid;

    for (int x = tid; x < 1312; x += 64) {
        int col = x - 128;
        bool valid = (col >= 1 && col <= 1023);
        int e = valid ? en[fwd ? col : 1024 - col] : 0;
        en_s[x] = e;
        wi_s[x] = valid ? W[AA + e] * INVLN2 : 0.0f;
    }

    const int r_src = (rr >= 1) ? (fwd ? rr : (1024 - rr)) : 0;
    const float mywd2 = (rr >= 1) ? W[ar[r_src]] * INVLN2 : 0.0f;
    {   // stage this lane's substitution row into LDS [e][tid] (scaled inline)
        const float* wrow = W + AA + EE + ((rr >= 1) ? (ar[r_src] << 8) : 0);
        #pragma unroll 8
        for (int i = 0; i < 64; ++i) {
            float4 w = *(const float4*)(wrow + (i << 2));
            ws_lds[((i << 2) + 0) * 64 + tid] = w.x * INVLN2;
            ws_lds[((i << 2) + 1) * 64 + tid] = w.y * INVLN2;
            ws_lds[((i << 2) + 2) * 64 + tid] = w.z * INVLN2;
            ws_lds[((i << 2) + 3) * 64 + tid] = w.w * INVLN2;
        }
    }

    if (SEED) {   // seed_s[x] = sum_{c=1..x} wi_s[128+c]
        float loc[16]; float s = 0.0f;
        #pragma unroll
        for (int i = 0; i < 16; ++i) {
            int x = (tid << 4) + i;
            float w = (x >= 1) ? wi_s[128 + x] : 0.0f;
            s += w; loc[i] = s;
        }
        float cum = s;
        for (int off = 1; off < 64; off <<= 1) {
            float tt = __shfl_up(cum, off);
            if (tid >= off) cum += tt;
        }
        float excl = cum - s;
        #pragma unroll
        for (int i = 0; i < 16; ++i) seed_s[(tid << 4) + i] = excl + loc[i];
    }
    __syncthreads();

    float* __restrict__ orow0 = fwd ? (alpha + ((size_t)rr << 10))
                                    : (betam + ((size_t)(1023 - rr) << 10));
    float* __restrict__ bnd_me = bnd + (size_t)dirb * 1024;
    const float* __restrict__ bnd_prev = bnd + (size_t)(dirb - 1) * 1024;
    const bool seedlane = SEED && (tid == 0);

    float vA = NINF, vB = NINF, upBp = NINF;
    int2   env[8];
    float2 wiv[4];
    float2 wsv[4];
    #pragma unroll
    for (int s = 0; s < 8; ++s) env[s] = *(const int2*)&en_s[128 + 2 * s - 2 * tid];
    #pragma unroll
    for (int s = 0; s < 4; ++s) wiv[s] = *(const float2*)&wi_s[128 + 2 * s - 2 * tid];
    #pragma unroll
    for (int s = 0; s < 4; ++s)
        wsv[s] = make_float2(ws_lds[(env[s].x << 6) + tid], ws_lds[(env[s].y << 6) + tid]);

    float bvals = NINF;

    auto body = [&](int c, int k, auto FULL_) {
        constexpr bool FULL = decltype(FULL_)::value;
        const int S = (c << 4) + k;
        const int sd = S - tid;                  // a = 2*sd
        const bool act = FULL || ((unsigned)sd < 512u);
        float bca = __int_as_float(__builtin_amdgcn_readlane(__float_as_int(bvals), 2 * k));
        float bcb = __int_as_float(__builtin_amdgcn_readlane(__float_as_int(bvals), 2 * k + 1));
        float upA = __int_as_float(__builtin_amdgcn_update_dpp(
            __float_as_int(bca), __float_as_int(vA), 0x138, 0xF, 0xF, false));
        float upB = __int_as_float(__builtin_amdgcn_update_dpp(
            __float_as_int(bcb), __float_as_int(vB), 0x138, 0xF, 0xF, false));
        float2 wsp = wsv[k & 3];
        float2 wip = wiv[k & 3];
        int2   ep  = *(const int2*)&en_s[128 + 2 * S + 16 - 2 * tid];    // for S+8
        float2 win = *(const float2*)&wi_s[128 + 2 * S + 8 - 2 * tid];   // for S+4
        int2   ec  = env[(k + 4) & 7];                                   // en for S+4
        float  wsx = ws_lds[(ec.x << 6) + tid];
        float  wsy = ws_lds[(ec.y << 6) + tid];

        // cell a
        float dela = mywd2 + upA;
        float suba = wsp.x + upBp;
        float insa = wip.x + vB;
        float VA = lse3(dela, suba, insa);
        if (SEED) VA = seedlane ? bca : VA;
        if (!FULL) VA = act ? VA : NINF;
        // cell b = a+1
        float delb = mywd2 + upB;
        float subb = wsp.y + upA;
        float insb = wip.y + VA;
        float VB = lse3(delb, subb, insb);
        if (SEED) VB = seedlane ? bcb : VB;
        if (!FULL) VB = act ? VB : NINF;

        env[(k + 8) & 7] = ep;
        wiv[(k + 4) & 3] = win;
        wsv[(k + 4) & 3] = make_float2(wsx, wsy);

        if (act) {
            const int a = 2 * sd;
            if (tid == 63)
                *(float2*)&pub[(a >> 5) & 1][a & 31] = make_float2(VA, VB);
            *(float2*)(orow0 + (sd << 1)) = make_float2(VA, VB);
        }
        upBp = upB; vA = VA; vB = VB;
    };

    for (int c = 0; c < NCHUNKS; ++c) {
        if (c <= 31) {
            if (SEED) {
                bvals = seed_s[(c << 5) + (tid & 31)];
            } else {
                const float* src = bnd_prev + (c << 5) + (tid & 31);
                unsigned x;
                for (;;) {
                    asm volatile("global_load_dword %0, %1, off sc0 sc1\n\t"
                                 "s_waitcnt vmcnt(0)"
                                 : "=v"(x) : "v"(src) : "memory");
                    if (__ballot(x != SENT) == ~0ull) break;
                    __builtin_amdgcn_s_sleep(1);
                }
                bvals = __uint_as_float(x);
            }
        }
        if (c >= 4 && c <= 31) {
            #pragma unroll
            for (int k = 0; k < 16; ++k) body(c, k, TrueT{});
        } else {
            #pragma unroll
            for (int k = 0; k < 16; ++k) body(c, k, FalseT{});
        }
        if (b < NSTRIP - 1 && c >= 4) {
            const int q = c - 4;
            float pv = pub[q & 1][tid & 31];
            if (tid < 32) {
                const float* dst = bnd_me + (q << 5) + tid;
                asm volatile("global_store_dword %0, %1, off sc0 sc1"
                             :: "v"(dst), "v"(__float_as_uint(pv)) : "memory");
            }
        }
    }
}

__global__ __launch_bounds__(64)
void k_dp_strip(const float* __restrict__ W, const int* __restrict__ ar,
                const int* __restrict__ en,
                float* __restrict__ alpha, float* __restrict__ betam,
                float* __restrict__ bnd) {
    __shared__ float ws_lds[256 * 64];          // [e][row], 64KB
    __shared__ float wi_s[1312];
    __shared__ int   en_s[1312];
    __shared__ float seed_s[1024];
    __shared__ float pub[2][32];
    const int tid = threadIdx.x;
    const int B = blockIdx.x;                   // 0..31
    const int xcd = B & 7, slot = B >> 3;
    const int dir = xcd >> 2;
    const int b = ((xcd & 3) << 2) + slot;      // strip 0..15
    const int dirb = (dir << 4) + b;
    const bool fwd = (dir == 0);
    if (b == 0)
        dp_run<true >(W, ar, en, alpha, betam, bnd, ws_lds, wi_s, en_s, seed_s, pub,
                      tid, dirb, b, fwd);
    else
        dp_run<false>(W, ar, en, alpha, betam, bnd, ws_lds, wi_s, en_s, seed_s, pub,
                      tid, dirb, b, fwd);
}

// ---------------- block sum helper (256 threads = 4 waves) ----------------
__device__ __forceinline__ float blk_sum(float v, float* sm) {
    for (int off = 32; off > 0; off >>= 1) v += __shfl_xor(v, off);
    if ((threadIdx.x & 63) == 0) sm[threadIdx.x >> 6] = v;
    __syncthreads();
    float r = sm[0] + sm[1] + sm[2] + sm[3];
    __syncthreads();
    return r;
}

// ---------------- fused epilogue pass 1 (linear Z-rescaled domain) ----------------
// Blocks 0..1022: row t=bi+1 -> rsum[t] = sum_j E2(alpha[t-1][j]+beta[t][j]-Z2)
//   (LINEAR rowred; no max pass needed since v <= Z + |w|) + sub e-bins in LDS.
// Blocks 1023..1150: colpart band partial: cps[band][j] = sum_t E2(v-Z2), branch-free.
__global__ __launch_bounds__(256)
void k_all(const float* __restrict__ alpha, const float* __restrict__ betam,
           const int* __restrict__ ar, const int* __restrict__ en,
           float* __restrict__ rowred, float* __restrict__ sbuf,
           float* __restrict__ cps) {
    const int bi = blockIdx.x;
    const int tid = threadIdx.x;
    if (bi < 1023) {
        __shared__ float als[1024];
        __shared__ float ebins[256];
        __shared__ float sm[4];
        const int t = bi + 1;
        const float Z2 = alpha[(size_t)1023 * 1024 + 1023];
        ebins[tid] = 0.0f;
        float al[4], bt[4];
        #pragma unroll
        for (int i = 0; i < 4; ++i) {
            int j = tid + (i << 8);
            al[i] = alpha[(size_t)(t - 1) * 1024 + j];
            bt[i] = betam[(size_t)t * 1024 + (1023 - j)];   // beta[t][j]
            als[j] = al[i];
        }
        __syncthreads();
        float s4 = 0.0f;
        #pragma unroll
        for (int i = 0; i < 4; ++i) s4 += E2(al[i] + bt[i] - Z2);
        float rs = blk_sum(s4, sm);
        if (tid == 0) rowred[t] = rs;            // linear-domain rsum
        // sub contributions -> LDS e-bins
        #pragma unroll
        for (int i = 0; i < 4; ++i) {
            int j = tid + (i << 8);
            if (j >= 1)
                atomicAdd(&ebins[en[j]], E2(als[j - 1] + bt[i] - Z2));
        }
        __syncthreads();
        atomicAdd(&sbuf[AA + EE + (ar[t] << 8) + tid], ebins[tid]);
    } else {
        __shared__ float smm[4][64];
        const float Z2 = alpha[(size_t)1023 * 1024 + 1023];
        int cp = bi - 1023;                 // 0..127
        int c = tid & 63;
        int g = tid >> 6;
        int j = ((cp & 15) << 6) + c;
        int t0 = (cp >> 4) << 7;
        float s = 0.0f;
        if (j >= 1) {
            for (int t = t0 + g; t < t0 + 128; t += 4)
                s += E2(alpha[(size_t)t * 1024 + (j - 1)]
                        + betam[(size_t)t * 1024 + (1023 - j)] - Z2);
        }
        smm[g][c] = s;
        __syncthreads();
        if (g == 0)
            cps[(size_t)(cp >> 4) * 1024 + j] = smm[0][c] + smm[1][c] + smm[2][c] + smm[3][c];
    }
}

// ---------------- fused epilogue pass 2 (all linear gathers, logs at the end) ----------------
// Blocks 0..255: sub-bin finalize. Block 256: dbins (sum rsum by ar — no exp2).
// Block 257: csum[j] = 8-band sum; ibins (sum csum by en — no exp2).
__global__ __launch_bounds__(256)
void k_fin(const float* __restrict__ W, const int* __restrict__ ar,
           const int* __restrict__ en, const float* __restrict__ rowred,
           const float* __restrict__ sbuf, const float* __restrict__ cps,
           const float* __restrict__ alpha, float* __restrict__ out) {
    const int blk = blockIdx.x;
    const int tid = threadIdx.x;
    const float Z2 = alpha[(size_t)1023 * 1024 + 1023];
    if (blk < 256) {
        int id = AA + EE + (blk << 8) + tid;
        float s = sbuf[id];
        out[id] = (s > 0.0f) ? safe_out(W[id] + LN2F * (Z2 + L2(s))) : NEGBIG;
        return;
    }
    if (blk == 256) {       // dbins: sum linear rsum by ar
        __shared__ float fv[1024]; __shared__ int iv[1024];
        for (int x = tid; x < 1024; x += 256) { fv[x] = rowred[x]; iv[x] = ar[x]; }
        __syncthreads();
        float s = 0.0f;
        for (int t = 1; t < 1024; ++t)
            if (iv[t] == tid) s += fv[t];
        out[tid] = (s > 0.0f) ? safe_out(W[tid] + LN2F * (Z2 + L2(s))) : NEGBIG;
    } else {                // csum + ibins
        __shared__ float cr[1024]; __shared__ int ev[1024];
        for (int jj = tid; jj < 1024; jj += 256) {
            float S = 0.0f;
            #pragma unroll
            for (int k = 0; k < 8; ++k) S += cps[(size_t)k * 1024 + jj];
            cr[jj] = S;
            ev[jj] = en[jj];
        }
        __syncthreads();
        float s = 0.0f;
        for (int j = 1; j < 1024; ++j)
            if (ev[j] == tid) s += cr[j];
        out[AA + tid] = (s > 0.0f) ? safe_out(W[AA + tid] + LN2F * (Z2 + L2(s))) : NEGBIG;
    }
}

extern "C" void kernel_launch(void* const* d_in, const int* in_sizes, int n_in,
                              void* d_out, int out_size, void* d_ws, size_t ws_size,
                              hipStream_t stream) {
    const float* W  = (const float*)d_in[0];
    const int*   ar = (const int*)d_in[1];
    const int*   en = (const int*)d_in[2];
    float* out = (float*)d_out;

    char* p = (char*)d_ws;
    float* alpha   = (float*)p; p += (size_t)TT * VV * 4;
    float* betam   = (float*)p; p += (size_t)TT * VV * 4;   // row-mirrored beta
    float* bnd     = (float*)p; p += (size_t)32 * 1024 * 4;
    float* rowred  = (float*)p; p += 1024 * 4;              // linear rsum
    float* cps     = (float*)p; p += (size_t)8 * 1024 * 4;  // linear band sums
    float* sbuf    = (float*)p; p += (size_t)CC * 4;

    k_init<<<dim3((CC + 255) / 256), dim3(256), 0, stream>>>(sbuf, (unsigned*)bnd);
    k_dp_strip<<<dim3(32), dim3(64), 0, stream>>>(W, ar, en, alpha, betam, bnd);
    k_all<<<dim3(1023 + 128), dim3(256), 0, stream>>>(alpha, betam, ar, en,
                                                      rowred, sbuf, cps);
    k_fin<<<dim3(258), dim3(256), 0, stream>>>(W, ar, en, rowred, sbuf, cps,
                                               alpha, out);
}

// Round 20
// 315.226 us; speedup vs baseline: 1.7806x; 1.1810x over previous
//
#include <hip/hip_runtime.h>

#define AA 256
#define EE 256
#define CC (AA + EE + AA*EE)   // 66048
#define TT 1024
#define VV 1024
#define NSTRIP 16
#define NCHUNKS 36             // 36 chunks x 16 supersteps = 576 supersteps
#define NEGBIG (-3.0e38f)      // finite stand-in for -inf in outputs
#define INVLN2 1.44269504088896340736f
#define LN2F   0.69314718055994530942f
#define SENT   0x7FC00001u     // NaN-payload sentinel for bnd
#define NINF   (-__builtin_inff())

#define E2(x) __builtin_amdgcn_exp2f(x)  // native v_exp_f32: 2^x
#define L2(x) __builtin_amdgcn_logf(x)   // native v_log_f32: log2(x)

struct TrueT  { static constexpr bool value = true;  };
struct FalseT { static constexpr bool value = false; };

__device__ __forceinline__ float safe_out(float v) {
    if (!(v > NEGBIG)) return NEGBIG;   // catches -inf, NaN
    return v;
}

__device__ __forceinline__ float lse3(float x, float y, float z) {
    float m3 = fmaxf(fmaxf(x, y), z);
    float me = __builtin_amdgcn_fmed3f(x, y, z);
    float mn = fminf(fminf(x, y), z);
    return m3 + L2(1.0f + E2(me - m3) + E2(mn - m3));
}

// ---------------- init: bnd sentinel + sbuf/dlin/ilin8 zero ----------------
__global__ void k_init(float* __restrict__ sbuf, unsigned* __restrict__ bndu) {
    int i = blockIdx.x * 256 + threadIdx.x;
    if (i < CC + 256 + 8 * 256) sbuf[i] = 0.0f;   // sbuf | dlin | ilin8 contiguous
    if (i < 32 * 1024) bndu[i] = SENT;
}

// ---------------- strip DP body (r17, FROZEN) ----------------
template<bool SEED>
__device__ __forceinline__ void dp_run(
        const float* __restrict__ W, const int* __restrict__ ar,
        const int* __restrict__ en,
        float* __restrict__ alpha, float* __restrict__ betam,
        float* __restrict__ bnd,
        float (&ws_lds)[256 * 64], float (&wi_s)[1312], int (&en_s)[1312],
        float (&seed_s)[1024], float (&pub)[2][32],
        int tid, int dirb, int b, bool fwd) {

    const int rr = (b << 6) + tid;

    for (int x = tid; x < 1312; x += 64) {
        int col = x - 128;
        bool valid = (col >= 1 && col <= 1023);
        int e = valid ? en[fwd ? col : 1024 - col] : 0;
        en_s[x] = e;
        wi_s[x] = valid ? W[AA + e] * INVLN2 : 0.0f;
    }

    const int r_src = (rr >= 1) ? (fwd ? rr : (1024 - rr)) : 0;
    const float mywd2 = (rr >= 1) ? W[ar[r_src]] * INVLN2 : 0.0f;
    {   // stage this lane's substitution row into LDS [e][tid] (scaled inline)
        const float* wrow = W + AA + EE + ((rr >= 1) ? (ar[r_src] << 8) : 0);
        #pragma unroll 8
        for (int i = 0; i < 64; ++i) {
            float4 w = *(const float4*)(wrow + (i << 2));
            ws_lds[((i << 2) + 0) * 64 + tid] = w.x * INVLN2;
            ws_lds[((i << 2) + 1) * 64 + tid] = w.y * INVLN2;
            ws_lds[((i << 2) + 2) * 64 + tid] = w.z * INVLN2;
            ws_lds[((i << 2) + 3) * 64 + tid] = w.w * INVLN2;
        }
    }

    if (SEED) {   // seed_s[x] = sum_{c=1..x} wi_s[128+c]
        float loc[16]; float s = 0.0f;
        #pragma unroll
        for (int i = 0; i < 16; ++i) {
            int x = (tid << 4) + i;
            float w = (x >= 1) ? wi_s[128 + x] : 0.0f;
            s += w; loc[i] = s;
        }
        float cum = s;
        for (int off = 1; off < 64; off <<= 1) {
            float tt = __shfl_up(cum, off);
            if (tid >= off) cum += tt;
        }
        float excl = cum - s;
        #pragma unroll
        for (int i = 0; i < 16; ++i) seed_s[(tid << 4) + i] = excl + loc[i];
    }
    __syncthreads();

    float* __restrict__ orow0 = fwd ? (alpha + ((size_t)rr << 10))
                                    : (betam + ((size_t)(1023 - rr) << 10));
    float* __restrict__ bnd_me = bnd + (size_t)dirb * 1024;
    const float* __restrict__ bnd_prev = bnd + (size_t)(dirb - 1) * 1024;
    const bool seedlane = SEED && (tid == 0);

    float vA = NINF, vB = NINF, upBp = NINF;
    int2   env[8];
    float2 wiv[4];
    float2 wsv[4];
    #pragma unroll
    for (int s = 0; s < 8; ++s) env[s] = *(const int2*)&en_s[128 + 2 * s - 2 * tid];
    #pragma unroll
    for (int s = 0; s < 4; ++s) wiv[s] = *(const float2*)&wi_s[128 + 2 * s - 2 * tid];
    #pragma unroll
    for (int s = 0; s < 4; ++s)
        wsv[s] = make_float2(ws_lds[(env[s].x << 6) + tid], ws_lds[(env[s].y << 6) + tid]);

    float bvals = NINF;

    auto body = [&](int c, int k, auto FULL_) {
        constexpr bool FULL = decltype(FULL_)::value;
        const int S = (c << 4) + k;
        const int sd = S - tid;                  // a = 2*sd
        const bool act = FULL || ((unsigned)sd < 512u);
        float bca = __int_as_float(__builtin_amdgcn_readlane(__float_as_int(bvals), 2 * k));
        float bcb = __int_as_float(__builtin_amdgcn_readlane(__float_as_int(bvals), 2 * k + 1));
        float upA = __int_as_float(__builtin_amdgcn_update_dpp(
            __float_as_int(bca), __float_as_int(vA), 0x138, 0xF, 0xF, false));
        float upB = __int_as_float(__builtin_amdgcn_update_dpp(
            __float_as_int(bcb), __float_as_int(vB), 0x138, 0xF, 0xF, false));
        float2 wsp = wsv[k & 3];
        float2 wip = wiv[k & 3];
        int2   ep  = *(const int2*)&en_s[128 + 2 * S + 16 - 2 * tid];    // for S+8
        float2 win = *(const float2*)&wi_s[128 + 2 * S + 8 - 2 * tid];   // for S+4
        int2   ec  = env[(k + 4) & 7];                                   // en for S+4
        float  wsx = ws_lds[(ec.x << 6) + tid];
        float  wsy = ws_lds[(ec.y << 6) + tid];

        // cell a
        float dela = mywd2 + upA;
        float suba = wsp.x + upBp;
        float insa = wip.x + vB;
        float VA = lse3(dela, suba, insa);
        if (SEED) VA = seedlane ? bca : VA;
        if (!FULL) VA = act ? VA : NINF;
        // cell b = a+1
        float delb = mywd2 + upB;
        float subb = wsp.y + upA;
        float insb = wip.y + VA;
        float VB = lse3(delb, subb, insb);
        if (SEED) VB = seedlane ? bcb : VB;
        if (!FULL) VB = act ? VB : NINF;

        env[(k + 8) & 7] = ep;
        wiv[(k + 4) & 3] = win;
        wsv[(k + 4) & 3] = make_float2(wsx, wsy);

        if (act) {
            const int a = 2 * sd;
            if (tid == 63)
                *(float2*)&pub[(a >> 5) & 1][a & 31] = make_float2(VA, VB);
            *(float2*)(orow0 + (sd << 1)) = make_float2(VA, VB);
        }
        upBp = upB; vA = VA; vB = VB;
    };

    for (int c = 0; c < NCHUNKS; ++c) {
        if (c <= 31) {
            if (SEED) {
                bvals = seed_s[(c << 5) + (tid & 31)];
            } else {
                const float* src = bnd_prev + (c << 5) + (tid & 31);
                unsigned x;
                for (;;) {
                    asm volatile("global_load_dword %0, %1, off sc0 sc1\n\t"
                                 "s_waitcnt vmcnt(0)"
                                 : "=v"(x) : "v"(src) : "memory");
                    if (__ballot(x != SENT) == ~0ull) break;
                    __builtin_amdgcn_s_sleep(1);
                }
                bvals = __uint_as_float(x);
            }
        }
        if (c >= 4 && c <= 31) {
            #pragma unroll
            for (int k = 0; k < 16; ++k) body(c, k, TrueT{});
        } else {
            #pragma unroll
            for (int k = 0; k < 16; ++k) body(c, k, FalseT{});
        }
        if (b < NSTRIP - 1 && c >= 4) {
            const int q = c - 4;
            float pv = pub[q & 1][tid & 31];
            if (tid < 32) {
                const float* dst = bnd_me + (q << 5) + tid;
                asm volatile("global_store_dword %0, %1, off sc0 sc1"
                             :: "v"(dst), "v"(__float_as_uint(pv)) : "memory");
            }
        }
    }
}

__global__ __launch_bounds__(64)
void k_dp_strip(const float* __restrict__ W, const int* __restrict__ ar,
                const int* __restrict__ en,
                float* __restrict__ alpha, float* __restrict__ betam,
                float* __restrict__ bnd) {
    __shared__ float ws_lds[256 * 64];          // [e][row], 64KB
    __shared__ float wi_s[1312];
    __shared__ int   en_s[1312];
    __shared__ float seed_s[1024];
    __shared__ float pub[2][32];
    const int tid = threadIdx.x;
    const int B = blockIdx.x;                   // 0..31
    const int xcd = B & 7, slot = B >> 3;
    const int dir = xcd >> 2;
    const int b = ((xcd & 3) << 2) + slot;      // strip 0..15
    const int dirb = (dir << 4) + b;
    const bool fwd = (dir == 0);
    if (b == 0)
        dp_run<true >(W, ar, en, alpha, betam, bnd, ws_lds, wi_s, en_s, seed_s, pub,
                      tid, dirb, b, fwd);
    else
        dp_run<false>(W, ar, en, alpha, betam, bnd, ws_lds, wi_s, en_s, seed_s, pub,
                      tid, dirb, b, fwd);
}

// ---------------- block sum helper (256 threads = 4 waves) ----------------
__device__ __forceinline__ float blk_sum(float v, float* sm) {
    for (int off = 32; off > 0; off >>= 1) v += __shfl_xor(v, off);
    if ((threadIdx.x & 63) == 0) sm[threadIdx.x >> 6] = v;
    __syncthreads();
    float r = sm[0] + sm[1] + sm[2] + sm[3];
    __syncthreads();
    return r;
}

// ---------------- single-pass fused epilogue (linear Z-rescaled domain) ----------------
// Block t (0..1023): loads beta[t], alpha[t] (insert), and alpha[t-1] (del/sub, t>=1).
//  del:  rsum_t = sum_j E2(alpha[t-1][j]+beta[t][j]-Z2)      -> dlin[ar[t]]   (1 atomic)
//  sub:  ebins[en[j]] += E2(alpha[t-1][j-1]+beta[t][j]-Z2)   -> sbuf[(a,e)]   (256 atomics)
//  ins:  ibins[en[j]] += E2(alpha[t][j-1]+beta[t][j]-Z2)     -> ilin8[t&7][e] (256 atomics)
__global__ __launch_bounds__(256)
void k_all(const float* __restrict__ alpha, const float* __restrict__ betam,
           const int* __restrict__ ar, const int* __restrict__ en,
           float* __restrict__ sbuf, float* __restrict__ dlin,
           float* __restrict__ ilin8) {
    __shared__ float alp[1024];   // alpha[t-1]
    __shared__ float ali[1024];   // alpha[t]
    __shared__ float ebins[256], ibins[256];
    __shared__ float sm[4];
    const int t = blockIdx.x;
    const int tid = threadIdx.x;
    const float Z2 = alpha[(size_t)1023 * 1024 + 1023];
    ebins[tid] = 0.0f;
    ibins[tid] = 0.0f;
    float bt[4];
    #pragma unroll
    for (int i = 0; i < 4; ++i) {
        int j = tid + (i << 8);
        bt[i] = betam[(size_t)t * 1024 + (1023 - j)];        // beta[t][j]
        ali[j] = alpha[(size_t)t * 1024 + j];
        if (t >= 1) alp[j] = alpha[(size_t)(t - 1) * 1024 + j];
    }
    __syncthreads();
    if (t >= 1) {
        float s4 = 0.0f;
        #pragma unroll
        for (int i = 0; i < 4; ++i) s4 += E2(alp[tid + (i << 8)] + bt[i] - Z2);
        float rs = blk_sum(s4, sm);
        if (tid == 0 && rs > 0.0f) atomicAdd(&dlin[ar[t]], rs);
        #pragma unroll
        for (int i = 0; i < 4; ++i) {
            int j = tid + (i << 8);
            if (j >= 1) {
                int e = en[j];
                atomicAdd(&ebins[e], E2(alp[j - 1] + bt[i] - Z2));
                atomicAdd(&ibins[e], E2(ali[j - 1] + bt[i] - Z2));
            }
        }
    } else {
        #pragma unroll
        for (int i = 0; i < 4; ++i) {
            int j = tid + (i << 8);
            if (j >= 1)
                atomicAdd(&ibins[en[j]], E2(ali[j - 1] + bt[i] - Z2));
        }
    }
    __syncthreads();
    if (t >= 1 && ebins[tid] > 0.0f)
        atomicAdd(&sbuf[AA + EE + (ar[t] << 8) + tid], ebins[tid]);
    if (ibins[tid] > 0.0f)
        atomicAdd(&ilin8[((t & 7) << 8) + tid], ibins[tid]);
}

// ---------------- finalize: all bins, fully parallel ----------------
// Blocks 0..255: sub bins. Block 256: dbins from dlin. Block 257: ibins from ilin8.
__global__ __launch_bounds__(256)
void k_fin(const float* __restrict__ W, const float* __restrict__ sbuf,
           const float* __restrict__ dlin, const float* __restrict__ ilin8,
           const float* __restrict__ alpha, float* __restrict__ out) {
    const int blk = blockIdx.x;
    const int tid = threadIdx.x;
    const float Z2 = alpha[(size_t)1023 * 1024 + 1023];
    if (blk < 256) {
        int id = AA + EE + (blk << 8) + tid;
        float s = sbuf[id];
        out[id] = (s > 0.0f) ? safe_out(W[id] + LN2F * (Z2 + L2(s))) : NEGBIG;
    } else if (blk == 256) {
        float s = dlin[tid];
        out[tid] = (s > 0.0f) ? safe_out(W[tid] + LN2F * (Z2 + L2(s))) : NEGBIG;
    } else {
        float s = 0.0f;
        #pragma unroll
        for (int k = 0; k < 8; ++k) s += ilin8[(k << 8) + tid];
        out[AA + tid] = (s > 0.0f) ? safe_out(W[AA + tid] + LN2F * (Z2 + L2(s))) : NEGBIG;
    }
}

extern "C" void kernel_launch(void* const* d_in, const int* in_sizes, int n_in,
                              void* d_out, int out_size, void* d_ws, size_t ws_size,
                              hipStream_t stream) {
    const float* W  = (const float*)d_in[0];
    const int*   ar = (const int*)d_in[1];
    const int*   en = (const int*)d_in[2];
    float* out = (float*)d_out;

    char* p = (char*)d_ws;
    float* alpha   = (float*)p; p += (size_t)TT * VV * 4;
    float* betam   = (float*)p; p += (size_t)TT * VV * 4;   // row-mirrored beta
    float* bnd     = (float*)p; p += (size_t)32 * 1024 * 4;
    float* sbuf    = (float*)p; p += (size_t)CC * 4;        // | dlin | ilin8 follow
    float* dlin    = (float*)p; p += 256 * 4;
    float* ilin8   = (float*)p; p += 8 * 256 * 4;

    k_init<<<dim3((CC + 256 + 2048 + 255) / 256), dim3(256), 0, stream>>>(sbuf, (unsigned*)bnd);
    k_dp_strip<<<dim3(32), dim3(64), 0, stream>>>(W, ar, en, alpha, betam, bnd);
    k_all<<<dim3(1024), dim3(256), 0, stream>>>(alpha, betam, ar, en, sbuf, dlin, ilin8);
    k_fin<<<dim3(258), dim3(256), 0, stream>>>(W, sbuf, dlin, ilin8, alpha, out);
}